// Round 10
// baseline (2427.889 us; speedup 1.0000x reference)
//
#include <hip/hip_runtime.h>
#include <hip/hip_bf16.h>

typedef __bf16 bf16x8 __attribute__((ext_vector_type(8)));
typedef float  f32x4  __attribute__((ext_vector_type(4)));
typedef unsigned long long u64;
using bf16 = __hip_bfloat16;

constexpr int Bv = 64, Tv = 128, Dv = 1024, Hv = 8, HDv = 128;
constexpr int NC = 1000, NS = 5, NM = 10;
constexpr int NT = Bv * Tv;           // 8192 tokens

static __device__ __forceinline__ float sigmoidf_(float x) {
  return 1.f / (1.f + __expf(-x));
}

static __device__ __forceinline__ void gload_lds16(const bf16* g, bf16* l) {
  __builtin_amdgcn_global_load_lds(
      (const __attribute__((address_space(1))) void*)g,
      (__attribute__((address_space(3))) void*)l, 16, 0, 0);
}

// ---------------- m97-structure GEMM: C[M,N] = A[M,K] @ W[N,K]^T + bias -------
__global__ __launch_bounds__(256) void gemm128(
    const bf16* __restrict__ A, const bf16* __restrict__ W,
    const float* __restrict__ bias, bf16* __restrict__ C,
    int M, int N, int K, int transT)
{
  __shared__ bf16 sa[128 * 32];
  __shared__ bf16 sb[128 * 32];
  int wave = threadIdx.x >> 6, lane = threadIdx.x & 63;
  int l15 = lane & 15, lhi = lane >> 4;
  int wr = wave >> 1, wc = wave & 1;
  int row0 = blockIdx.x * 128, col0 = blockIdx.y * 128;
  f32x4 acc[4][4];
#pragma unroll
  for (int m = 0; m < 4; ++m)
#pragma unroll
    for (int n = 0; n < 4; ++n) acc[m][n] = f32x4{0.f, 0.f, 0.f, 0.f};

  int sr = wave * 32 + (lane >> 2);
  int sk = (lane & 3) * 8;
  const bf16* srcA = A + (size_t)(row0 + sr) * K + sk;
  const bf16* srcB = W + (size_t)(col0 + sr) * K + sk;
  bf16* dstA0 = &sa[wave * 1024];
  bf16* dstB0 = &sb[wave * 1024];

  for (int k0 = 0; k0 < K; k0 += 32) {
    __syncthreads();
    gload_lds16(srcA + k0,            dstA0);
    gload_lds16(srcA + 16 * K + k0,   dstA0 + 512);
    gload_lds16(srcB + k0,            dstB0);
    gload_lds16(srcB + 16 * K + k0,   dstB0 + 512);
    __syncthreads();
    bf16x8 af[4], bfr[4];
#pragma unroll
    for (int m = 0; m < 4; ++m)
      af[m] = *reinterpret_cast<const bf16x8*>(&sa[(wr * 64 + m * 16 + l15) * 32 + lhi * 8]);
#pragma unroll
    for (int n = 0; n < 4; ++n)
      bfr[n] = *reinterpret_cast<const bf16x8*>(&sb[(wc * 64 + n * 16 + l15) * 32 + lhi * 8]);
#pragma unroll
    for (int m = 0; m < 4; ++m)
#pragma unroll
      for (int n = 0; n < 4; ++n)
        acc[m][n] = __builtin_amdgcn_mfma_f32_16x16x32_bf16(af[m], bfr[n], acc[m][n], 0, 0, 0);
  }

#pragma unroll
  for (int n = 0; n < 4; ++n) {
    int col = col0 + wc * 64 + n * 16 + l15;
    float bv = bias ? bias[col] : 0.f;
#pragma unroll
    for (int m = 0; m < 4; ++m) {
#pragma unroll
      for (int r = 0; r < 4; ++r) {
        int row = row0 + wr * 64 + m * 16 + lhi * 4 + r;
        int orow = transT ? ((row & (Tv - 1)) * Bv + (row >> 7)) : row;
        C[(size_t)orow * N + col] = __float2bfloat16(acc[m][n][r] + bv);
      }
    }
  }
}

// ---------------- f32 -> bf16 convert ----------------
__global__ void f2b_kernel(const float* __restrict__ s, bf16* __restrict__ d, int n4)
{
  int i = blockIdx.x * 256 + threadIdx.x;
  if (i < n4) {
    float4 v = ((const float4*)s)[i];
    bf16* o = d + (size_t)i * 4;
    o[0] = __float2bfloat16(v.x); o[1] = __float2bfloat16(v.y);
    o[2] = __float2bfloat16(v.z); o[3] = __float2bfloat16(v.w);
  }
}

__global__ void add2_kernel(const float* __restrict__ a, const float* __restrict__ b,
                            float* __restrict__ o, int n)
{
  int i = blockIdx.x * 256 + threadIdx.x;
  if (i < n) o[i] = a[i] + b[i];
}

// ---------------- emb table: 640 distinct (t, stage) rows ----------------
__global__ __launch_bounds__(128) void emb_kernel(
    const float* __restrict__ w1, const float* __restrict__ b1,
    const float* __restrict__ g1, const float* __restrict__ bb1,
    const float* __restrict__ w2, const float* __restrict__ b2,
    const float* __restrict__ g2, const float* __restrict__ bb2,
    float* __restrict__ emb)
{
  int combo = blockIdx.x;                 // t*5 + s
  float tpos = (float)(combo / 5);
  float stg  = (float)(combo % 5);
  int tid = threadIdx.x;
  __shared__ float hb[64];
  __shared__ float rs[4];
  if (tid < 64) {
    float v = w1[tid * 2] * tpos + w1[tid * 2 + 1] * stg + b1[tid];
    float s = v, s2 = v * v;
    for (int off = 32; off; off >>= 1) { s += __shfl_down(s, off); s2 += __shfl_down(s2, off); }
    s = __shfl(s, 0); s2 = __shfl(s2, 0);
    float mu = s / 64.f, var = s2 / 64.f - mu * mu;
    float h = (v - mu) * rsqrtf(var + 1e-5f) * g1[tid] + bb1[tid];
    hb[tid] = fmaxf(h, 0.f);
  }
  __syncthreads();
  float outv[8];
  float s = 0.f, s2 = 0.f;
  int d0 = tid * 8;
#pragma unroll
  for (int o = 0; o < 8; ++o) {
    int d = d0 + o;
    float acc = b2[d];
    const float4* wr = (const float4*)(w2 + (size_t)d * 64);
#pragma unroll
    for (int k4 = 0; k4 < 16; ++k4) {
      float4 w = wr[k4];
      acc += w.x * hb[k4 * 4] + w.y * hb[k4 * 4 + 1] + w.z * hb[k4 * 4 + 2] + w.w * hb[k4 * 4 + 3];
    }
    outv[o] = acc; s += acc; s2 += acc * acc;
  }
  for (int off = 32; off; off >>= 1) { s += __shfl_down(s, off); s2 += __shfl_down(s2, off); }
  int wid = tid >> 6;
  if ((tid & 63) == 0) { rs[wid] = s; rs[2 + wid] = s2; }
  __syncthreads();
  s = rs[0] + rs[1]; s2 = rs[2] + rs[3];
  float mu = s / 1024.f, var = s2 / 1024.f - mu * mu;
  float rstd = rsqrtf(var + 1e-5f);
  float* op = emb + (size_t)combo * Dv + d0;
#pragma unroll
  for (int o = 0; o < 8; ++o) {
    int d = d0 + o;
    op[o] = (outv[o] - mu) * rstd * g2[d] + bb2[d];
  }
}

__global__ __launch_bounds__(256) void addemb_kernel(
    const float* __restrict__ x, const int* __restrict__ stage,
    const float* __restrict__ emb, bf16* __restrict__ xpe)
{
  int tok = blockIdx.x;
  int row = (tok & (Tv - 1)) * NS + stage[tok];
  const float4* xr = (const float4*)(x + (size_t)tok * Dv);
  const float4* er = (const float4*)(emb + (size_t)row * Dv);
  bf16* op = xpe + (size_t)tok * Dv + threadIdx.x * 4;
  float4 xv = xr[threadIdx.x], ev = er[threadIdx.x];
  op[0] = __float2bfloat16(xv.x + ev.x);
  op[1] = __float2bfloat16(xv.y + ev.y);
  op[2] = __float2bfloat16(xv.z + ev.z);
  op[3] = __float2bfloat16(xv.w + ev.w);
}

// ---------------- attention: per (b,h) flash-style, scalar fp32 ----------------
__global__ __launch_bounds__(256) void attn_kernel(const bf16* __restrict__ qkv,
                                                   bf16* __restrict__ o)
{
  __shared__ bf16 kl[128][128];
  __shared__ bf16 vl[128][128];
  int bh = blockIdx.x;
  int b = bh >> 3, h = bh & 7;
  int tid = threadIdx.x;
  int row = tid >> 1, hf = tid & 1;
  {
    const bf16* ks = qkv + (size_t)(b * Tv + row) * 3072 + Dv + h * HDv + hf * 64;
    const bf16* vs = ks + Dv;
    uint4* dk = (uint4*)&kl[row][hf * 64];
    uint4* dv = (uint4*)&vl[row][hf * 64];
    const uint4* sk = (const uint4*)ks;
    const uint4* sv = (const uint4*)vs;
#pragma unroll
    for (int i = 0; i < 8; ++i) { dk[i] = sk[i]; dv[i] = sv[i]; }
  }
  float qf[64];
  {
    const bf16* qs = qkv + (size_t)(b * Tv + row) * 3072 + h * HDv + hf * 64;
#pragma unroll
    for (int d2 = 0; d2 < 32; ++d2) {
      float2 f = __bfloat1622float2(*(const __hip_bfloat162*)(qs + 2 * d2));
      qf[2 * d2] = f.x; qf[2 * d2 + 1] = f.y;
    }
  }
  __syncthreads();
  float oacc[64];
#pragma unroll
  for (int d = 0; d < 64; ++d) oacc[d] = 0.f;
  float m = -1e30f, l = 0.f;
  const float scale = 0.088388347648318447f;  // 1/sqrt(128)
  for (int j = 0; j < 128; ++j) {
    float part = 0.f;
#pragma unroll
    for (int d2 = 0; d2 < 32; ++d2) {
      float2 kv2 = __bfloat1622float2(*(const __hip_bfloat162*)&kl[j][hf * 64 + 2 * d2]);
      part += qf[2 * d2] * kv2.x + qf[2 * d2 + 1] * kv2.y;
    }
    float sfull = (part + __shfl_xor(part, 1)) * scale;
    float mn = fmaxf(m, sfull);
    float al = __expf(m - mn);
    float p = __expf(sfull - mn);
    l = l * al + p;
#pragma unroll
    for (int d2 = 0; d2 < 32; ++d2) {
      float2 vv = __bfloat1622float2(*(const __hip_bfloat162*)&vl[j][hf * 64 + 2 * d2]);
      oacc[2 * d2]     = oacc[2 * d2] * al + p * vv.x;
      oacc[2 * d2 + 1] = oacc[2 * d2 + 1] * al + p * vv.y;
    }
    m = mn;
  }
  float rl = 1.f / l;
  bf16* od = o + (size_t)(b * Tv + row) * Dv + h * HDv + hf * 64;
#pragma unroll
  for (int d = 0; d < 64; ++d) od[d] = __float2bfloat16(oacc[d] * rl);
}

// ---------------- residual + LN -> raw (f32 to d_out) + raw16 -----------------
__global__ __launch_bounds__(256) void residual_ln_kernel(
    const bf16* __restrict__ xpe, const bf16* __restrict__ ao,
    const float* __restrict__ gam, const float* __restrict__ bet,
    float* __restrict__ rawf, bf16* __restrict__ raw16)
{
  int tok = blockIdx.x, tid = threadIdx.x;
  float v[4]; float s = 0.f, s2 = 0.f;
  __shared__ float rs[8];
#pragma unroll
  for (int q = 0; q < 4; ++q) {
    int d = tid + q * 256;
    size_t idx = (size_t)tok * Dv + d;
    float a = __bfloat162float(xpe[idx]) + __bfloat162float(ao[idx]);
    v[q] = a; s += a; s2 += a * a;
  }
  for (int off = 32; off; off >>= 1) { s += __shfl_down(s, off); s2 += __shfl_down(s2, off); }
  int wid = tid >> 6;
  if ((tid & 63) == 0) { rs[wid] = s; rs[4 + wid] = s2; }
  __syncthreads();
  s = rs[0] + rs[1] + rs[2] + rs[3];
  s2 = rs[4] + rs[5] + rs[6] + rs[7];
  float mu = s / 1024.f, var = s2 / 1024.f - mu * mu;
  float rstd = rsqrtf(var + 1e-5f);
#pragma unroll
  for (int q = 0; q < 4; ++q) {
    int d = tid + q * 256;
    size_t idx = (size_t)tok * Dv + d;
    float rv = (v[q] - mu) * rstd * gam[d] + bet[d];
    rawf[idx] = rv;
    raw16[idx] = __float2bfloat16(rv);
  }
}

// ---------------- fused 2-layer pipelined persistent LSTM (v10) ---------------
// Grid 256 x 512 (8 waves: gate g = wave&3, K-half kh = wave>>2).
// Block (gid, j): batches gid*16..+15, units j*16..+15, both layers.
// Whh0/Wih1 slices pinned into AGPRs ("a" constraint, 128 AGPR/wave) — the
// unified-file path the allocator can't undo (r2-r9: "+v" pins were
// re-streamed from L2 every step; VGPR_Count=124 proved it). Whh1 streams
// from L2 (XCD-co-located, ~1 MB distinct per XCD). MFMA reads A/B directly
// from AGPR (ISA §10).
// Barrier structure: S1 poll+sync, S2 stage, S3 gl-handoff, S4 hst-handoff.
// NO S5: wave0 performs both h-chunk stores, drains its own vmcnt, sets flag.
__global__ __launch_bounds__(512, 1) void lstm_fused(
    const bf16* __restrict__ Whh0, const bf16* __restrict__ Wih1,
    const bf16* __restrict__ Whh1, const bf16* __restrict__ xgT,
    const float* __restrict__ bsum1,
    bf16* h0buf, bf16* h1buf,
    float* __restrict__ pooled, int* flags)
{
  const int bid = blockIdx.x;
  const int xcd = bid & 7, idx = bid >> 3;
  const int j   = xcd * 8 + (idx & 7);   // unit block 0..63
  const int gid = idx >> 3;              // batch group 0..3
  const int u0  = j * 16;
  const int tid = threadIdx.x;
  const int wave = tid >> 6, lane = tid & 63;
  const int g = wave & 3, kh = wave >> 2;
  const int l15 = lane & 15, lhi = lane >> 4;
  const int koff = lhi * 8;

  // AGPR-resident weight slices (rows g*Dv+u0+l15, K-half kh): Whh0 + Wih1.
  bf16x8 w0h[16], w1h[16];
  {
    const size_t rowoff = (size_t)(g * Dv + u0 + l15) * Dv + kh * 512 + koff;
    const bf16* r0 = Whh0 + rowoff;
    const bf16* r1 = Wih1 + rowoff;
#pragma unroll
    for (int i = 0; i < 16; ++i) {
      w0h[i] = *reinterpret_cast<const bf16x8*>(r0 + i * 32);
      w1h[i] = *reinterpret_cast<const bf16x8*>(r1 + i * 32);
    }
#pragma unroll
    for (int i = 0; i < 16; ++i) {     // pin into AGPRs: opaque + off the VGPR budget
      asm volatile("" : "+a"(w0h[i]));
      asm volatile("" : "+a"(w1h[i]));
    }
  }
  const bf16* rh1 = Whh1 + (size_t)(g * Dv + u0 + l15) * Dv + kh * 512 + koff;
  const float bs1 = bsum1[g * Dv + u0 + l15];

  __shared__ bf16 hA[16 * 2056];       // [batch][0..1023 h0 | 1024..2047 h1 | pad]
  __shared__ float gl0[2][4][16][16];  // [kh][gate][batch][unit]
  __shared__ float gl1[2][4][16][16];
  __shared__ bf16 hst0[256];
  __shared__ bf16 hst1[256];

  const int bb_t = (tid & 255) >> 4, uu_t = tid & 15;
  float c0 = 0.f, c1 = 0.f;
  int* gflags = flags + gid * 64;

  for (int s = 0; s <= Tv; ++s) {
    // ---- xg prefetch for L0 t=s (kh==0 waves carry it) ----
    float xv[4] = {0.f, 0.f, 0.f, 0.f};
    if (s < Tv && kh == 0) {
      const bf16* xg_t = xgT + (size_t)s * (Bv * 4 * Dv)
                         + (size_t)(gid * 16) * (4 * Dv) + g * Dv + u0 + l15;
#pragma unroll
      for (int r = 0; r < 4; ++r)
        xv[r] = __bfloat162float(xg_t[(size_t)(lhi * 4 + r) * (4 * Dv)]);
    }
    // ---- barrier: all 64 group flags >= s ----
    if (s > 0) {
      if (tid < 64) {
        while (true) {
          int v = __hip_atomic_load(gflags + tid, __ATOMIC_RELAXED, __HIP_MEMORY_SCOPE_AGENT);
          if (__all(v >= s)) break;
          __builtin_amdgcn_s_sleep(1);
        }
      }
      __syncthreads();                                   // S1
      // ---- stage h0(s-1) + h1(s-2) into LDS (sc1 loads) ----
      {
        const u64* s0 = (const u64*)h0buf + (size_t)(((s - 1) & 1) * 4 + gid) * 4096;
        u64* dA = (u64*)hA;
#pragma unroll
        for (int it = 0; it < 8; ++it) {
          int id = it * 512 + tid;
          int jc = id >> 6, r = id & 63, bb = r >> 2, uq = r & 3;
          u64 v = __hip_atomic_load(s0 + id, __ATOMIC_RELAXED, __HIP_MEMORY_SCOPE_AGENT);
          dA[bb * 514 + jc * 4 + uq] = v;
        }
        if (s >= 2) {
          const u64* s1 = (const u64*)h1buf + (size_t)(((s - 2) & 1) * 4 + gid) * 4096;
#pragma unroll
          for (int it = 0; it < 8; ++it) {
            int id = it * 512 + tid;
            int jc = id >> 6, r = id & 63, bb = r >> 2, uq = r & 3;
            u64 v = __hip_atomic_load(s1 + id, __ATOMIC_RELAXED, __HIP_MEMORY_SCOPE_AGENT);
            dA[bb * 514 + 256 + jc * 4 + uq] = v;
          }
        }
      }
      __syncthreads();                                   // S2
    }

    // ================= layer 0: t = s (K-half partial) =================
    if (s < Tv) {
      f32x4 acc = f32x4{0.f, 0.f, 0.f, 0.f};
      if (s > 0) {
#pragma unroll
        for (int i = 0; i < 16; ++i) {
          bf16x8 a = *reinterpret_cast<const bf16x8*>(&hA[l15 * 2056 + kh * 512 + i * 32 + koff]);
          acc = __builtin_amdgcn_mfma_f32_16x16x32_bf16(a, w0h[i], acc, 0, 0, 0);
        }
      }
#pragma unroll
      for (int r = 0; r < 4; ++r)
        gl0[kh][g][lhi * 4 + r][l15] = acc[r] + xv[r];
    }
    // ================= layer 1: t = s-1 (K-half partial) =================
    if (s > 0) {
      f32x4 acc = f32x4{0.f, 0.f, 0.f, 0.f};
#pragma unroll
      for (int i = 0; i < 16; ++i) {                     // y0 term (Wih1, AGPR)
        bf16x8 a = *reinterpret_cast<const bf16x8*>(&hA[l15 * 2056 + kh * 512 + i * 32 + koff]);
        acc = __builtin_amdgcn_mfma_f32_16x16x32_bf16(a, w1h[i], acc, 0, 0, 0);
      }
      if (s >= 2) {
#pragma unroll
        for (int i = 0; i < 16; ++i) {                   // h1 term (Whh1, L2 stream)
          bf16x8 b = *reinterpret_cast<const bf16x8*>(rh1 + i * 32);
          bf16x8 a = *reinterpret_cast<const bf16x8*>(&hA[l15 * 2056 + 1024 + kh * 512 + i * 32 + koff]);
          acc = __builtin_amdgcn_mfma_f32_16x16x32_bf16(a, b, acc, 0, 0, 0);
        }
      }
#pragma unroll
      for (int r = 0; r < 4; ++r)
        gl1[kh][g][lhi * 4 + r][l15] = acc[r] + (kh == 0 ? bs1 : 0.f);
    }
    __syncthreads();                                     // S3
    // ---- gates: combine K-halves, nonlinearity, c/h update ----
    if (tid < 256) {
      if (s < Tv) {
        float gi = gl0[0][0][bb_t][uu_t] + gl0[1][0][bb_t][uu_t];
        float gf = gl0[0][1][bb_t][uu_t] + gl0[1][1][bb_t][uu_t];
        float gc = gl0[0][2][bb_t][uu_t] + gl0[1][2][bb_t][uu_t];
        float go = gl0[0][3][bb_t][uu_t] + gl0[1][3][bb_t][uu_t];
        float cn = sigmoidf_(gf) * c0 + sigmoidf_(gi) * tanhf(gc);
        float hn = sigmoidf_(go) * tanhf(cn);
        c0 = cn;
        hst0[bb_t * 16 + uu_t] = __float2bfloat16(hn);
      }
      if (s > 0) {
        float gi = gl1[0][0][bb_t][uu_t] + gl1[1][0][bb_t][uu_t];
        float gf = gl1[0][1][bb_t][uu_t] + gl1[1][1][bb_t][uu_t];
        float gc = gl1[0][2][bb_t][uu_t] + gl1[1][2][bb_t][uu_t];
        float go = gl1[0][3][bb_t][uu_t] + gl1[1][3][bb_t][uu_t];
        float cn = sigmoidf_(gf) * c1 + sigmoidf_(gi) * tanhf(gc);
        float hn = sigmoidf_(go) * tanhf(cn);
        c1 = cn;
        hst1[bb_t * 16 + uu_t] = __float2bfloat16(hn);
        if (s == Tv) pooled[(gid * 16 + bb_t) * Dv + u0 + uu_t] = hn;
      }
    }
    __syncthreads();                                     // S4
    // ---- wave0: both h-chunk stores, own-wave drain, flag (no block barrier) --
    if (tid < 64) {
      if (s < Tv) {
        u64* dst0 = (u64*)h0buf + (size_t)((s & 1) * 4 + gid) * 4096 + j * 64 + tid;
        __hip_atomic_store(dst0, ((u64*)hst0)[tid], __ATOMIC_RELAXED, __HIP_MEMORY_SCOPE_AGENT);
      }
      if (s > 0 && s < Tv) {    // h1(Tv-1) is never read -> skip at s==Tv
        u64* dst1 = (u64*)h1buf + (size_t)(((s - 1) & 1) * 4 + gid) * 4096 + j * 64 + tid;
        __hip_atomic_store(dst1, ((u64*)hst1)[tid], __ATOMIC_RELAXED, __HIP_MEMORY_SCOPE_AGENT);
      }
      if (s < Tv) {
        asm volatile("s_waitcnt vmcnt(0)" ::: "memory"); // wave-level drain of the 2 stores
        if (tid == 0)
          __hip_atomic_store(gflags + j, s + 1, __ATOMIC_RELAXED, __HIP_MEMORY_SCOPE_AGENT);
      }
    }
  }
}

// ---------------- raw_mean over T ----------------
__global__ void rawmean_kernel(const float* __restrict__ raw, float* __restrict__ out)
{
  int i = blockIdx.x * 256 + threadIdx.x;   // 65536
  int b = i >> 10, d = i & 1023;
  const float* r = raw + (size_t)b * Tv * Dv + d;
  float s = 0.f;
  for (int t = 0; t < Tv; ++t) s += r[(size_t)t * Dv];
  out[i] = s * (1.f / Tv);
}

// ---------------- gated fusion ----------------
__global__ __launch_bounds__(256) void gate1_kernel(
    const float* __restrict__ pooled, const float* __restrict__ rawmean,
    const float* __restrict__ w1, const float* __restrict__ b1, float* __restrict__ out)
{
  int b = blockIdx.x;
  __shared__ float cat[2048];
  for (int k = threadIdx.x; k < 1024; k += 256) {
    cat[k] = pooled[b * 1024 + k];
    cat[1024 + k] = rawmean[b * 1024 + k];
  }
  __syncthreads();
  for (int jj = 0; jj < 4; ++jj) {
    int j = threadIdx.x + jj * 256;
    float acc = b1[j];
    const float4* wr = (const float4*)(w1 + (size_t)j * 2048);
    for (int k4 = 0; k4 < 512; ++k4) {
      float4 w = wr[k4];
      acc += w.x * cat[k4 * 4] + w.y * cat[k4 * 4 + 1] + w.z * cat[k4 * 4 + 2] + w.w * cat[k4 * 4 + 3];
    }
    out[b * 1024 + j] = fmaxf(acc, 0.f);
  }
}

__global__ __launch_bounds__(256) void gate2_kernel(
    const float* __restrict__ gt1, const float* __restrict__ pooled,
    const float* __restrict__ rawmean,
    const float* __restrict__ w2, const float* __restrict__ b2, float* __restrict__ fused)
{
  int b = blockIdx.x;
  __shared__ float cl[1024];
  for (int k = threadIdx.x; k < 1024; k += 256) cl[k] = gt1[b * 1024 + k];
  __syncthreads();
  for (int jj = 0; jj < 4; ++jj) {
    int j = threadIdx.x + jj * 256;
    float acc = b2[j];
    const float4* wr = (const float4*)(w2 + (size_t)j * 1024);
    for (int k4 = 0; k4 < 256; ++k4) {
      float4 w = wr[k4];
      acc += w.x * cl[k4 * 4] + w.y * cl[k4 * 4 + 1] + w.z * cl[k4 * 4 + 2] + w.w * cl[k4 * 4 + 3];
    }
    float gv = sigmoidf_(acc);
    int idx = b * 1024 + j;
    fused[idx] = gv * pooled[idx] + (1.f - gv) * rawmean[idx];
  }
}

// ---------------- stage head ----------------
__global__ __launch_bounds__(128) void head_kernel(
    const float* __restrict__ fused,
    const float* __restrict__ w1, const float* __restrict__ b1,
    const float* __restrict__ gam, const float* __restrict__ bet,
    const float* __restrict__ w2, const float* __restrict__ b2,
    float* __restrict__ logits)
{
  int b = blockIdx.x;
  __shared__ float fl[1024];
  __shared__ float h1[512];
  __shared__ float rs[4];
  for (int k = threadIdx.x; k < 1024; k += 128) fl[k] = fused[b * 1024 + k];
  __syncthreads();
  float vals[4]; float s = 0.f, s2 = 0.f;
  for (int jj = 0; jj < 4; ++jj) {
    int j = threadIdx.x + jj * 128;
    float acc = b1[j];
    const float4* wr = (const float4*)(w1 + (size_t)j * 1024);
    for (int k4 = 0; k4 < 256; ++k4) {
      float4 w = wr[k4];
      acc += w.x * fl[k4 * 4] + w.y * fl[k4 * 4 + 1] + w.z * fl[k4 * 4 + 2] + w.w * fl[k4 * 4 + 3];
    }
    vals[jj] = acc; s += acc; s2 += acc * acc;
  }
  for (int off = 32; off; off >>= 1) { s += __shfl_down(s, off); s2 += __shfl_down(s2, off); }
  int wid = threadIdx.x >> 6;
  if ((threadIdx.x & 63) == 0) { rs[wid] = s; rs[2 + wid] = s2; }
  __syncthreads();
  s = rs[0] + rs[1]; s2 = rs[2] + rs[3];
  float mu = s / 512.f, var = s2 / 512.f - mu * mu;
  float rstd = rsqrtf(var + 1e-5f);
  for (int jj = 0; jj < 4; ++jj) {
    int j = threadIdx.x + jj * 128;
    h1[j] = fmaxf((vals[jj] - mu) * rstd * gam[j] + bet[j], 0.f);
  }
  __syncthreads();
  if (threadIdx.x < 5) {
    float acc = b2[threadIdx.x];
    for (int k = 0; k < 512; ++k) acc += h1[k] * w2[threadIdx.x * 512 + k];
    logits[b * 5 + threadIdx.x] = acc;
  }
}

// ---------------- memory bank update ----------------
__global__ void scatter_last_kernel(const int* __restrict__ cls,
                                    const int* __restrict__ stage, int* __restrict__ last)
{
  int i = blockIdx.x * 256 + threadIdx.x;
  if (i < NT) {
    int b = i >> 7;
    int p = cls[b] * NS + stage[i];
    atomicMax(&last[p], i);
  }
}

__global__ __launch_bounds__(256) void mem_update_kernel(
    const float* __restrict__ mem_in, const float* __restrict__ raw,
    const int* __restrict__ cnt_in, const int* __restrict__ last,
    float* __restrict__ mem_out, float* __restrict__ cnt_out)
{
  int p = blockIdx.x;
  int cnt = cnt_in[p];
  int li = last[p];
  bool present = li >= 0;
  bool full = cnt >= NM;
  int wp = full ? NM - 1 : cnt;
  const float* newf = raw + (size_t)(li < 0 ? 0 : li) * Dv;
  const float* src = mem_in + (size_t)p * NM * Dv;
  float* dst = mem_out + (size_t)p * NM * Dv;
  for (int idx = threadIdx.x; idx < NM * Dv / 4; idx += 256) {
    int m = idx >> 8;          // 256 float4 per row
    int dq = idx & 255;
    float4 v;
    if (present && full) {
      v = (m < NM - 1) ? *(const float4*)(src + (size_t)(m + 1) * Dv + dq * 4)
                       : *(const float4*)(newf + dq * 4);
    } else if (present) {
      v = (m == wp) ? *(const float4*)(newf + dq * 4)
                    : *(const float4*)(src + (size_t)m * Dv + dq * 4);
    } else {
      v = *(const float4*)(src + (size_t)m * Dv + dq * 4);
    }
    *(float4*)(dst + (size_t)m * Dv + dq * 4) = v;
  }
  if (threadIdx.x == 0)
    cnt_out[p] = (float)(cnt + ((present && !full) ? 1 : 0));
}

// =======================================================================
extern "C" void kernel_launch(void* const* d_in, const int* in_sizes, int n_in,
                              void* d_out, int out_size, void* d_ws, size_t ws_size,
                              hipStream_t stream)
{
  (void)in_sizes; (void)n_in; (void)out_size; (void)ws_size;
  const float* x       = (const float*)d_in[0];
  const int* stage     = (const int*)d_in[1];
  const int* cls       = (const int*)d_in[2];
  const float* enc_w1  = (const float*)d_in[3];
  const float* enc_b1  = (const float*)d_in[4];
  const float* enc_g1  = (const float*)d_in[5];
  const float* enc_bb1 = (const float*)d_in[6];
  const float* enc_w2  = (const float*)d_in[7];
  const float* enc_b2  = (const float*)d_in[8];
  const float* enc_g2  = (const float*)d_in[9];
  const float* enc_bb2 = (const float*)d_in[10];
  const float* qkv_w   = (const float*)d_in[11];
  const float* qkv_b   = (const float*)d_in[12];
  const float* out_w   = (const float*)d_in[13];
  const float* out_b   = (const float*)d_in[14];
  const float* norm_g  = (const float*)d_in[15];
  const float* norm_b  = (const float*)d_in[16];
  const float* Wih0    = (const float*)d_in[17];
  const float* Whh0    = (const float*)d_in[18];
  const float* bih0    = (const float*)d_in[19];
  const float* bhh0    = (const float*)d_in[20];
  const float* Wih1    = (const float*)d_in[21];
  const float* Whh1    = (const float*)d_in[22];
  const float* bih1    = (const float*)d_in[23];
  const float* bhh1    = (const float*)d_in[24];
  const float* head_w1 = (const float*)d_in[25];
  const float* head_b1 = (const float*)d_in[26];
  const float* head_g  = (const float*)d_in[27];
  const float* head_bb = (const float*)d_in[28];
  const float* head_w2 = (const float*)d_in[29];
  const float* head_b2 = (const float*)d_in[30];
  const float* gate_w1 = (const float*)d_in[31];
  const float* gate_b1 = (const float*)d_in[32];
  const float* gate_w2 = (const float*)d_in[33];
  const float* gate_b2 = (const float*)d_in[34];
  const float* mem_in  = (const float*)d_in[35];
  const int* cnt_in    = (const int*)d_in[36];

  float* out = (float*)d_out;
  float* out_fused  = out;                      // 65536
  float* out_raw    = out + 65536;              // 8388608
  float* out_logits = out + 8454144;            // 320
  float* out_mem    = out + 8454464;            // 51200000
  float* out_cnt    = out + 59654464;           // 5000

  // ---- workspace layout (bf16 weights + small state), ~42 MB ----
  char* wsb = (char*)d_ws;
  auto alloc = [&](size_t bytes) { char* p = wsb; wsb += (bytes + 255) & ~(size_t)255; return p; };
  bf16* wq16   = (bf16*)alloc((size_t)3072 * 1024 * 2);
  bf16* wo16   = (bf16*)alloc((size_t)1024 * 1024 * 2);
  bf16* wih0b  = (bf16*)alloc((size_t)4096 * 1024 * 2);
  bf16* whh0b  = (bf16*)alloc((size_t)4096 * 1024 * 2);
  bf16* wih1b  = (bf16*)alloc((size_t)4096 * 1024 * 2);
  bf16* whh1b  = (bf16*)alloc((size_t)4096 * 1024 * 2);
  float* bsum0 = (float*)alloc(4096 * 4);
  float* bsum1 = (float*)alloc(4096 * 4);
  bf16* h0buf  = (bf16*)alloc((size_t)2 * 4 * 16384 * 2);  // [parity][gid]: 4096 u64 each
  bf16* h1buf  = (bf16*)alloc((size_t)2 * 4 * 16384 * 2);
  float* pooled  = (float*)alloc(65536 * 4);
  float* rawmean = (float*)alloc(65536 * 4);
  float* gt1     = (float*)alloc(65536 * 4);
  int* last      = (int*)alloc(5000 * 4);
  int* flags     = (int*)alloc(1024);            // 4 groups x 64 ints

  // ---- large activation scratch inside the new_mem output slot (204.8 MB) ----
  char* orb = (char*)out_mem;
  bf16* qkv16 = (bf16*)(orb + 0);            // 50,331,648 B
  bf16* xgT   = (bf16*)(orb + 67108864);     // 67,108,864 B  [t][b][4096]
  bf16* xpe16 = (bf16*)(orb + 134217728);    // 16,777,216 B
  bf16* o16   = (bf16*)(orb + 150994944);    // 16,777,216 B
  bf16* ao16  = (bf16*)(orb + 167772160);    // 16,777,216 B
  bf16* raw16 = (bf16*)(orb + 184549376);    // 16,777,216 B (ends 201,326,592)
  float* embf = (float*)(orb + 201326592);   //  2,621,440 B (ends 203,948,032)

  // 1) weight conversions + bias sums
  f2b_kernel<<<3072, 256, 0, stream>>>(qkv_w, wq16, 786432);
  f2b_kernel<<<1024, 256, 0, stream>>>(out_w, wo16, 262144);
  f2b_kernel<<<4096, 256, 0, stream>>>(Wih0, wih0b, 1048576);
  f2b_kernel<<<4096, 256, 0, stream>>>(Whh0, whh0b, 1048576);
  f2b_kernel<<<4096, 256, 0, stream>>>(Wih1, wih1b, 1048576);
  f2b_kernel<<<4096, 256, 0, stream>>>(Whh1, whh1b, 1048576);
  add2_kernel<<<16, 256, 0, stream>>>(bih0, bhh0, bsum0, 4096);
  add2_kernel<<<16, 256, 0, stream>>>(bih1, bhh1, bsum1, 4096);

  // 2) encoder: 640-row emb table, then fused add -> xpe16
  emb_kernel<<<Tv * NS, 128, 0, stream>>>(enc_w1, enc_b1, enc_g1, enc_bb1,
                                          enc_w2, enc_b2, enc_g2, enc_bb2, embf);
  addemb_kernel<<<NT, 256, 0, stream>>>(x, stage, embf, xpe16);

  // 3) qkv = xpe @ qkv_w^T + b
  gemm128<<<dim3(NT / 128, 3072 / 128), 256, 0, stream>>>(xpe16, wq16, qkv_b, qkv16,
                                                          NT, 3072, Dv, 0);

  // 4) attention -> o16
  attn_kernel<<<Bv * Hv, 256, 0, stream>>>(qkv16, o16);

  // 5) out projection -> ao16
  gemm128<<<dim3(NT / 128, 1024 / 128), 256, 0, stream>>>(o16, wo16, out_b, ao16,
                                                          NT, Dv, Dv, 0);

  // 6) residual + LN -> raw (d_out) + raw16
  residual_ln_kernel<<<NT, 256, 0, stream>>>(xpe16, ao16, norm_g, norm_b, out_raw, raw16);

  // 7) layer-0 input gates (time-major), then fused 2-layer recurrence
  gemm128<<<dim3(NT / 128, 4096 / 128), 256, 0, stream>>>(raw16, wih0b, bsum0, xgT,
                                                          NT, 4096, Dv, 1);
  hipMemsetAsync(flags, 0, 1024, stream);
  lstm_fused<<<256, 512, 0, stream>>>(whh0b, wih1b, whh1b, xgT, bsum1,
                                      h0buf, h1buf, pooled, flags);

  // 8) raw_mean, gated fusion, head
  rawmean_kernel<<<256, 256, 0, stream>>>(out_raw, rawmean);
  gate1_kernel<<<Bv, 256, 0, stream>>>(pooled, rawmean, gate_w1, gate_b1, gt1);
  gate2_kernel<<<Bv, 256, 0, stream>>>(gt1, pooled, rawmean, gate_w2, gate_b2, out_fused);
  head_kernel<<<Bv, 128, 0, stream>>>(out_fused, head_w1, head_b1, head_g, head_bb,
                                      head_w2, head_b2, out_logits);

  // 9) memory bank update (overwrites the scratch region last)
  hipMemsetAsync(last, 0xFF, 5000 * 4, stream);
  scatter_last_kernel<<<32, 256, 0, stream>>>(cls, stage, last);
  mem_update_kernel<<<NC * NS, 256, 0, stream>>>(mem_in, out_raw, cnt_in, last, out_mem, out_cnt);
}

// Round 11
// 2397.668 us; speedup vs baseline: 1.0126x; 1.0126x over previous
//
#include <hip/hip_runtime.h>
#include <hip/hip_bf16.h>

typedef __bf16 bf16x8 __attribute__((ext_vector_type(8)));
typedef float  f32x4  __attribute__((ext_vector_type(4)));
typedef unsigned long long u64;
using bf16 = __hip_bfloat16;

constexpr int Bv = 64, Tv = 128, Dv = 1024, Hv = 8, HDv = 128;
constexpr int NC = 1000, NS = 5, NM = 10;
constexpr int NT = Bv * Tv;           // 8192 tokens

static __device__ __forceinline__ float sigmoidf_(float x) {
  return 1.f / (1.f + __expf(-x));
}

static __device__ __forceinline__ void gload_lds16(const bf16* g, bf16* l) {
  __builtin_amdgcn_global_load_lds(
      (const __attribute__((address_space(1))) void*)g,
      (__attribute__((address_space(3))) void*)l, 16, 0, 0);
}

// ---------------- m97-structure GEMM: C[M,N] = A[M,K] @ W[N,K]^T + bias -------
__global__ __launch_bounds__(256) void gemm128(
    const bf16* __restrict__ A, const bf16* __restrict__ W,
    const float* __restrict__ bias, bf16* __restrict__ C,
    int M, int N, int K, int transT)
{
  __shared__ bf16 sa[128 * 32];
  __shared__ bf16 sb[128 * 32];
  int wave = threadIdx.x >> 6, lane = threadIdx.x & 63;
  int l15 = lane & 15, lhi = lane >> 4;
  int wr = wave >> 1, wc = wave & 1;
  int row0 = blockIdx.x * 128, col0 = blockIdx.y * 128;
  f32x4 acc[4][4];
#pragma unroll
  for (int m = 0; m < 4; ++m)
#pragma unroll
    for (int n = 0; n < 4; ++n) acc[m][n] = f32x4{0.f, 0.f, 0.f, 0.f};

  int sr = wave * 32 + (lane >> 2);
  int sk = (lane & 3) * 8;
  const bf16* srcA = A + (size_t)(row0 + sr) * K + sk;
  const bf16* srcB = W + (size_t)(col0 + sr) * K + sk;
  bf16* dstA0 = &sa[wave * 1024];
  bf16* dstB0 = &sb[wave * 1024];

  for (int k0 = 0; k0 < K; k0 += 32) {
    __syncthreads();
    gload_lds16(srcA + k0,            dstA0);
    gload_lds16(srcA + 16 * K + k0,   dstA0 + 512);
    gload_lds16(srcB + k0,            dstB0);
    gload_lds16(srcB + 16 * K + k0,   dstB0 + 512);
    __syncthreads();
    bf16x8 af[4], bfr[4];
#pragma unroll
    for (int m = 0; m < 4; ++m)
      af[m] = *reinterpret_cast<const bf16x8*>(&sa[(wr * 64 + m * 16 + l15) * 32 + lhi * 8]);
#pragma unroll
    for (int n = 0; n < 4; ++n)
      bfr[n] = *reinterpret_cast<const bf16x8*>(&sb[(wc * 64 + n * 16 + l15) * 32 + lhi * 8]);
#pragma unroll
    for (int m = 0; m < 4; ++m)
#pragma unroll
      for (int n = 0; n < 4; ++n)
        acc[m][n] = __builtin_amdgcn_mfma_f32_16x16x32_bf16(af[m], bfr[n], acc[m][n], 0, 0, 0);
  }

#pragma unroll
  for (int n = 0; n < 4; ++n) {
    int col = col0 + wc * 64 + n * 16 + l15;
    float bv = bias ? bias[col] : 0.f;
#pragma unroll
    for (int m = 0; m < 4; ++m) {
#pragma unroll
      for (int r = 0; r < 4; ++r) {
        int row = row0 + wr * 64 + m * 16 + lhi * 4 + r;
        int orow = transT ? ((row & (Tv - 1)) * Bv + (row >> 7)) : row;
        C[(size_t)orow * N + col] = __float2bfloat16(acc[m][n][r] + bv);
      }
    }
  }
}

// ---------------- f32 -> bf16 convert ----------------
__global__ void f2b_kernel(const float* __restrict__ s, bf16* __restrict__ d, int n4)
{
  int i = blockIdx.x * 256 + threadIdx.x;
  if (i < n4) {
    float4 v = ((const float4*)s)[i];
    bf16* o = d + (size_t)i * 4;
    o[0] = __float2bfloat16(v.x); o[1] = __float2bfloat16(v.y);
    o[2] = __float2bfloat16(v.z); o[3] = __float2bfloat16(v.w);
  }
}

__global__ void add2_kernel(const float* __restrict__ a, const float* __restrict__ b,
                            float* __restrict__ o, int n)
{
  int i = blockIdx.x * 256 + threadIdx.x;
  if (i < n) o[i] = a[i] + b[i];
}

// ---------------- emb table: 640 distinct (t, stage) rows ----------------
__global__ __launch_bounds__(128) void emb_kernel(
    const float* __restrict__ w1, const float* __restrict__ b1,
    const float* __restrict__ g1, const float* __restrict__ bb1,
    const float* __restrict__ w2, const float* __restrict__ b2,
    const float* __restrict__ g2, const float* __restrict__ bb2,
    float* __restrict__ emb)
{
  int combo = blockIdx.x;                 // t*5 + s
  float tpos = (float)(combo / 5);
  float stg  = (float)(combo % 5);
  int tid = threadIdx.x;
  __shared__ float hb[64];
  __shared__ float rs[4];
  if (tid < 64) {
    float v = w1[tid * 2] * tpos + w1[tid * 2 + 1] * stg + b1[tid];
    float s = v, s2 = v * v;
    for (int off = 32; off; off >>= 1) { s += __shfl_down(s, off); s2 += __shfl_down(s2, off); }
    s = __shfl(s, 0); s2 = __shfl(s2, 0);
    float mu = s / 64.f, var = s2 / 64.f - mu * mu;
    float h = (v - mu) * rsqrtf(var + 1e-5f) * g1[tid] + bb1[tid];
    hb[tid] = fmaxf(h, 0.f);
  }
  __syncthreads();
  float outv[8];
  float s = 0.f, s2 = 0.f;
  int d0 = tid * 8;
#pragma unroll
  for (int o = 0; o < 8; ++o) {
    int d = d0 + o;
    float acc = b2[d];
    const float4* wr = (const float4*)(w2 + (size_t)d * 64);
#pragma unroll
    for (int k4 = 0; k4 < 16; ++k4) {
      float4 w = wr[k4];
      acc += w.x * hb[k4 * 4] + w.y * hb[k4 * 4 + 1] + w.z * hb[k4 * 4 + 2] + w.w * hb[k4 * 4 + 3];
    }
    outv[o] = acc; s += acc; s2 += acc * acc;
  }
  for (int off = 32; off; off >>= 1) { s += __shfl_down(s, off); s2 += __shfl_down(s2, off); }
  int wid = tid >> 6;
  if ((tid & 63) == 0) { rs[wid] = s; rs[2 + wid] = s2; }
  __syncthreads();
  s = rs[0] + rs[1]; s2 = rs[2] + rs[3];
  float mu = s / 1024.f, var = s2 / 1024.f - mu * mu;
  float rstd = rsqrtf(var + 1e-5f);
  float* op = emb + (size_t)combo * Dv + d0;
#pragma unroll
  for (int o = 0; o < 8; ++o) {
    int d = d0 + o;
    op[o] = (outv[o] - mu) * rstd * g2[d] + bb2[d];
  }
}

__global__ __launch_bounds__(256) void addemb_kernel(
    const float* __restrict__ x, const int* __restrict__ stage,
    const float* __restrict__ emb, bf16* __restrict__ xpe)
{
  int tok = blockIdx.x;
  int row = (tok & (Tv - 1)) * NS + stage[tok];
  const float4* xr = (const float4*)(x + (size_t)tok * Dv);
  const float4* er = (const float4*)(emb + (size_t)row * Dv);
  bf16* op = xpe + (size_t)tok * Dv + threadIdx.x * 4;
  float4 xv = xr[threadIdx.x], ev = er[threadIdx.x];
  op[0] = __float2bfloat16(xv.x + ev.x);
  op[1] = __float2bfloat16(xv.y + ev.y);
  op[2] = __float2bfloat16(xv.z + ev.z);
  op[3] = __float2bfloat16(xv.w + ev.w);
}

// ---------------- attention: per (b,h) flash-style, scalar fp32 ----------------
__global__ __launch_bounds__(256) void attn_kernel(const bf16* __restrict__ qkv,
                                                   bf16* __restrict__ o)
{
  __shared__ bf16 kl[128][128];
  __shared__ bf16 vl[128][128];
  int bh = blockIdx.x;
  int b = bh >> 3, h = bh & 7;
  int tid = threadIdx.x;
  int row = tid >> 1, hf = tid & 1;
  {
    const bf16* ks = qkv + (size_t)(b * Tv + row) * 3072 + Dv + h * HDv + hf * 64;
    const bf16* vs = ks + Dv;
    uint4* dk = (uint4*)&kl[row][hf * 64];
    uint4* dv = (uint4*)&vl[row][hf * 64];
    const uint4* sk = (const uint4*)ks;
    const uint4* sv = (const uint4*)vs;
#pragma unroll
    for (int i = 0; i < 8; ++i) { dk[i] = sk[i]; dv[i] = sv[i]; }
  }
  float qf[64];
  {
    const bf16* qs = qkv + (size_t)(b * Tv + row) * 3072 + h * HDv + hf * 64;
#pragma unroll
    for (int d2 = 0; d2 < 32; ++d2) {
      float2 f = __bfloat1622float2(*(const __hip_bfloat162*)(qs + 2 * d2));
      qf[2 * d2] = f.x; qf[2 * d2 + 1] = f.y;
    }
  }
  __syncthreads();
  float oacc[64];
#pragma unroll
  for (int d = 0; d < 64; ++d) oacc[d] = 0.f;
  float m = -1e30f, l = 0.f;
  const float scale = 0.088388347648318447f;  // 1/sqrt(128)
  for (int j = 0; j < 128; ++j) {
    float part = 0.f;
#pragma unroll
    for (int d2 = 0; d2 < 32; ++d2) {
      float2 kv2 = __bfloat1622float2(*(const __hip_bfloat162*)&kl[j][hf * 64 + 2 * d2]);
      part += qf[2 * d2] * kv2.x + qf[2 * d2 + 1] * kv2.y;
    }
    float sfull = (part + __shfl_xor(part, 1)) * scale;
    float mn = fmaxf(m, sfull);
    float al = __expf(m - mn);
    float p = __expf(sfull - mn);
    l = l * al + p;
#pragma unroll
    for (int d2 = 0; d2 < 32; ++d2) {
      float2 vv = __bfloat1622float2(*(const __hip_bfloat162*)&vl[j][hf * 64 + 2 * d2]);
      oacc[2 * d2]     = oacc[2 * d2] * al + p * vv.x;
      oacc[2 * d2 + 1] = oacc[2 * d2 + 1] * al + p * vv.y;
    }
    m = mn;
  }
  float rl = 1.f / l;
  bf16* od = o + (size_t)(b * Tv + row) * Dv + h * HDv + hf * 64;
#pragma unroll
  for (int d = 0; d < 64; ++d) od[d] = __float2bfloat16(oacc[d] * rl);
}

// ---------------- residual + LN -> raw (f32 to d_out) + raw16 -----------------
__global__ __launch_bounds__(256) void residual_ln_kernel(
    const bf16* __restrict__ xpe, const bf16* __restrict__ ao,
    const float* __restrict__ gam, const float* __restrict__ bet,
    float* __restrict__ rawf, bf16* __restrict__ raw16)
{
  int tok = blockIdx.x, tid = threadIdx.x;
  float v[4]; float s = 0.f, s2 = 0.f;
  __shared__ float rs[8];
#pragma unroll
  for (int q = 0; q < 4; ++q) {
    int d = tid + q * 256;
    size_t idx = (size_t)tok * Dv + d;
    float a = __bfloat162float(xpe[idx]) + __bfloat162float(ao[idx]);
    v[q] = a; s += a; s2 += a * a;
  }
  for (int off = 32; off; off >>= 1) { s += __shfl_down(s, off); s2 += __shfl_down(s2, off); }
  int wid = tid >> 6;
  if ((tid & 63) == 0) { rs[wid] = s; rs[4 + wid] = s2; }
  __syncthreads();
  s = rs[0] + rs[1] + rs[2] + rs[3];
  s2 = rs[4] + rs[5] + rs[6] + rs[7];
  float mu = s / 1024.f, var = s2 / 1024.f - mu * mu;
  float rstd = rsqrtf(var + 1e-5f);
#pragma unroll
  for (int q = 0; q < 4; ++q) {
    int d = tid + q * 256;
    size_t idx = (size_t)tok * Dv + d;
    float rv = (v[q] - mu) * rstd * gam[d] + bet[d];
    rawf[idx] = rv;
    raw16[idx] = __float2bfloat16(rv);
  }
}

// ---------------- fused 2-layer pipelined persistent LSTM (v11) ---------------
// Grid 256 x 512 (8 waves: gate g = wave&3, K-half kh = wave>>2).
// Block (gid, j): batches gid*16..+15, units j*16..+15, both layers.
// Whh0/Wih1 slices live in AGPRs, CONSUMED DIRECTLY by inline-asm MFMA with
// the "a" operand constraint (ISA §10: B may be AGPR). r10's failure: "+a"
// pin + VGPR-wanting intrinsic -> per-use copies. Now the use site demands
// AGPR, so residency is the cheapest allocation. 128 AGPR + ~124 VGPR ≈ 252
// unified regs @ 8 waves/CU. Whh1 streams from L2 (XCD-co-located).
// Barrier structure identical to r9 (proven): S1 poll, S2 stage, S3, S4, S5.
__global__ __launch_bounds__(512, 1) void lstm_fused(
    const bf16* __restrict__ Whh0, const bf16* __restrict__ Wih1,
    const bf16* __restrict__ Whh1, const bf16* __restrict__ xgT,
    const float* __restrict__ bsum1,
    bf16* h0buf, bf16* h1buf,
    float* __restrict__ pooled, int* flags)
{
  const int bid = blockIdx.x;
  const int xcd = bid & 7, idx = bid >> 3;
  const int j   = xcd * 8 + (idx & 7);   // unit block 0..63
  const int gid = idx >> 3;              // batch group 0..3
  const int u0  = j * 16;
  const int tid = threadIdx.x;
  const int wave = tid >> 6, lane = tid & 63;
  const int g = wave & 3, kh = wave >> 2;
  const int l15 = lane & 15, lhi = lane >> 4;
  const int koff = lhi * 8;

  // AGPR-resident weight slices (rows g*Dv+u0+l15, K-half kh): Whh0 + Wih1.
  bf16x8 w0h[16], w1h[16];
  {
    const size_t rowoff = (size_t)(g * Dv + u0 + l15) * Dv + kh * 512 + koff;
    const bf16* r0 = Whh0 + rowoff;
    const bf16* r1 = Wih1 + rowoff;
#pragma unroll
    for (int i = 0; i < 16; ++i) {
      w0h[i] = *reinterpret_cast<const bf16x8*>(r0 + i * 32);
      w1h[i] = *reinterpret_cast<const bf16x8*>(r1 + i * 32);
    }
#pragma unroll
    for (int i = 0; i < 16; ++i) {     // seed allocation into AGPRs
      asm volatile("" : "+a"(w0h[i]));
      asm volatile("" : "+a"(w1h[i]));
    }
  }
  const bf16* rh1 = Whh1 + (size_t)(g * Dv + u0 + l15) * Dv + kh * 512 + koff;
  const float bs1 = bsum1[g * Dv + u0 + l15];

  __shared__ bf16 hA[16 * 2056];       // [batch][0..1023 h0 | 1024..2047 h1 | pad]
  __shared__ float gl0[2][4][16][16];  // [kh][gate][batch][unit]
  __shared__ float gl1[2][4][16][16];
  __shared__ bf16 hst0[256];
  __shared__ bf16 hst1[256];

  const int bb_t = (tid & 255) >> 4, uu_t = tid & 15;
  float c0 = 0.f, c1 = 0.f;
  int* gflags = flags + gid * 64;

  for (int s = 0; s <= Tv; ++s) {
    // ---- xg prefetch for L0 t=s (kh==0 waves carry it) ----
    float xv[4] = {0.f, 0.f, 0.f, 0.f};
    if (s < Tv && kh == 0) {
      const bf16* xg_t = xgT + (size_t)s * (Bv * 4 * Dv)
                         + (size_t)(gid * 16) * (4 * Dv) + g * Dv + u0 + l15;
#pragma unroll
      for (int r = 0; r < 4; ++r)
        xv[r] = __bfloat162float(xg_t[(size_t)(lhi * 4 + r) * (4 * Dv)]);
    }
    // ---- barrier: all 64 group flags >= s ----
    if (s > 0) {
      if (tid < 64) {
        while (true) {
          int v = __hip_atomic_load(gflags + tid, __ATOMIC_RELAXED, __HIP_MEMORY_SCOPE_AGENT);
          if (__all(v >= s)) break;
          __builtin_amdgcn_s_sleep(1);
        }
      }
      __syncthreads();                                   // S1
      // ---- stage h0(s-1) + h1(s-2) into LDS (sc1 loads) ----
      {
        const u64* s0 = (const u64*)h0buf + (size_t)(((s - 1) & 1) * 4 + gid) * 4096;
        u64* dA = (u64*)hA;
#pragma unroll
        for (int it = 0; it < 8; ++it) {
          int id = it * 512 + tid;
          int jc = id >> 6, r = id & 63, bb = r >> 2, uq = r & 3;
          u64 v = __hip_atomic_load(s0 + id, __ATOMIC_RELAXED, __HIP_MEMORY_SCOPE_AGENT);
          dA[bb * 514 + jc * 4 + uq] = v;
        }
        if (s >= 2) {
          const u64* s1 = (const u64*)h1buf + (size_t)(((s - 2) & 1) * 4 + gid) * 4096;
#pragma unroll
          for (int it = 0; it < 8; ++it) {
            int id = it * 512 + tid;
            int jc = id >> 6, r = id & 63, bb = r >> 2, uq = r & 3;
            u64 v = __hip_atomic_load(s1 + id, __ATOMIC_RELAXED, __HIP_MEMORY_SCOPE_AGENT);
            dA[bb * 514 + 256 + jc * 4 + uq] = v;
          }
        }
      }
      __syncthreads();                                   // S2
    }

    // ================= layer 0: t = s (K-half partial) =================
    if (s < Tv) {
      f32x4 acc = f32x4{0.f, 0.f, 0.f, 0.f};
      if (s > 0) {
#pragma unroll
        for (int i = 0; i < 16; ++i) {
          bf16x8 a = *reinterpret_cast<const bf16x8*>(&hA[l15 * 2056 + kh * 512 + i * 32 + koff]);
          asm("v_mfma_f32_16x16x32_bf16 %0, %1, %2, %0"
              : "+v"(acc) : "v"(a), "a"(w0h[i]));
        }
      }
#pragma unroll
      for (int r = 0; r < 4; ++r)
        gl0[kh][g][lhi * 4 + r][l15] = acc[r] + xv[r];
    }
    // ================= layer 1: t = s-1 (K-half partial) =================
    if (s > 0) {
      f32x4 acc = f32x4{0.f, 0.f, 0.f, 0.f};
#pragma unroll
      for (int i = 0; i < 16; ++i) {                     // y0 term (Wih1, AGPR)
        bf16x8 a = *reinterpret_cast<const bf16x8*>(&hA[l15 * 2056 + kh * 512 + i * 32 + koff]);
        asm("v_mfma_f32_16x16x32_bf16 %0, %1, %2, %0"
            : "+v"(acc) : "v"(a), "a"(w1h[i]));
      }
      if (s >= 2) {
#pragma unroll
        for (int i = 0; i < 16; ++i) {                   // h1 term (Whh1, L2 stream)
          bf16x8 b = *reinterpret_cast<const bf16x8*>(rh1 + i * 32);
          bf16x8 a = *reinterpret_cast<const bf16x8*>(&hA[l15 * 2056 + 1024 + kh * 512 + i * 32 + koff]);
          acc = __builtin_amdgcn_mfma_f32_16x16x32_bf16(a, b, acc, 0, 0, 0);
        }
      }
#pragma unroll
      for (int r = 0; r < 4; ++r)
        gl1[kh][g][lhi * 4 + r][l15] = acc[r] + (kh == 0 ? bs1 : 0.f);
    }
    __syncthreads();                                     // S3
    // ---- gates: combine K-halves, nonlinearity, c/h update ----
    if (tid < 256) {
      if (s < Tv) {
        float gi = gl0[0][0][bb_t][uu_t] + gl0[1][0][bb_t][uu_t];
        float gf = gl0[0][1][bb_t][uu_t] + gl0[1][1][bb_t][uu_t];
        float gc = gl0[0][2][bb_t][uu_t] + gl0[1][2][bb_t][uu_t];
        float go = gl0[0][3][bb_t][uu_t] + gl0[1][3][bb_t][uu_t];
        float cn = sigmoidf_(gf) * c0 + sigmoidf_(gi) * tanhf(gc);
        float hn = sigmoidf_(go) * tanhf(cn);
        c0 = cn;
        hst0[bb_t * 16 + uu_t] = __float2bfloat16(hn);
      }
      if (s > 0) {
        float gi = gl1[0][0][bb_t][uu_t] + gl1[1][0][bb_t][uu_t];
        float gf = gl1[0][1][bb_t][uu_t] + gl1[1][1][bb_t][uu_t];
        float gc = gl1[0][2][bb_t][uu_t] + gl1[1][2][bb_t][uu_t];
        float go = gl1[0][3][bb_t][uu_t] + gl1[1][3][bb_t][uu_t];
        float cn = sigmoidf_(gf) * c1 + sigmoidf_(gi) * tanhf(gc);
        float hn = sigmoidf_(go) * tanhf(cn);
        c1 = cn;
        hst1[bb_t * 16 + uu_t] = __float2bfloat16(hn);
        if (s == Tv) pooled[(gid * 16 + bb_t) * Dv + u0 + uu_t] = hn;
      }
    }
    __syncthreads();                                     // S4
    // ---- sc1 stores of h chunks ----
    if (s < Tv && tid < 64) {
      u64* dst = (u64*)h0buf + (size_t)((s & 1) * 4 + gid) * 4096 + j * 64 + tid;
      __hip_atomic_store(dst, ((u64*)hst0)[tid], __ATOMIC_RELAXED, __HIP_MEMORY_SCOPE_AGENT);
    }
    if (s > 0 && tid >= 64 && tid < 128) {
      int q = tid - 64;
      u64* dst = (u64*)h1buf + (size_t)(((s - 1) & 1) * 4 + gid) * 4096 + j * 64 + q;
      __hip_atomic_store(dst, ((u64*)hst1)[q], __ATOMIC_RELAXED, __HIP_MEMORY_SCOPE_AGENT);
    }
    // ---- drain + flag ----
    if (s < Tv) {
      asm volatile("s_waitcnt vmcnt(0)" ::: "memory");
      __syncthreads();                                   // S5
      if (tid == 0)
        __hip_atomic_store(gflags + j, s + 1, __ATOMIC_RELAXED, __HIP_MEMORY_SCOPE_AGENT);
    }
  }
}

// ---------------- raw_mean over T ----------------
__global__ void rawmean_kernel(const float* __restrict__ raw, float* __restrict__ out)
{
  int i = blockIdx.x * 256 + threadIdx.x;   // 65536
  int b = i >> 10, d = i & 1023;
  const float* r = raw + (size_t)b * Tv * Dv + d;
  float s = 0.f;
  for (int t = 0; t < Tv; ++t) s += r[(size_t)t * Dv];
  out[i] = s * (1.f / Tv);
}

// ---------------- gated fusion ----------------
__global__ __launch_bounds__(256) void gate1_kernel(
    const float* __restrict__ pooled, const float* __restrict__ rawmean,
    const float* __restrict__ w1, const float* __restrict__ b1, float* __restrict__ out)
{
  int b = blockIdx.x;
  __shared__ float cat[2048];
  for (int k = threadIdx.x; k < 1024; k += 256) {
    cat[k] = pooled[b * 1024 + k];
    cat[1024 + k] = rawmean[b * 1024 + k];
  }
  __syncthreads();
  for (int jj = 0; jj < 4; ++jj) {
    int j = threadIdx.x + jj * 256;
    float acc = b1[j];
    const float4* wr = (const float4*)(w1 + (size_t)j * 2048);
    for (int k4 = 0; k4 < 512; ++k4) {
      float4 w = wr[k4];
      acc += w.x * cat[k4 * 4] + w.y * cat[k4 * 4 + 1] + w.z * cat[k4 * 4 + 2] + w.w * cat[k4 * 4 + 3];
    }
    out[b * 1024 + j] = fmaxf(acc, 0.f);
  }
}

__global__ __launch_bounds__(256) void gate2_kernel(
    const float* __restrict__ gt1, const float* __restrict__ pooled,
    const float* __restrict__ rawmean,
    const float* __restrict__ w2, const float* __restrict__ b2, float* __restrict__ fused)
{
  int b = blockIdx.x;
  __shared__ float cl[1024];
  for (int k = threadIdx.x; k < 1024; k += 256) cl[k] = gt1[b * 1024 + k];
  __syncthreads();
  for (int jj = 0; jj < 4; ++jj) {
    int j = threadIdx.x + jj * 256;
    float acc = b2[j];
    const float4* wr = (const float4*)(w2 + (size_t)j * 1024);
    for (int k4 = 0; k4 < 256; ++k4) {
      float4 w = wr[k4];
      acc += w.x * cl[k4 * 4] + w.y * cl[k4 * 4 + 1] + w.z * cl[k4 * 4 + 2] + w.w * cl[k4 * 4 + 3];
    }
    float gv = sigmoidf_(acc);
    int idx = b * 1024 + j;
    fused[idx] = gv * pooled[idx] + (1.f - gv) * rawmean[idx];
  }
}

// ---------------- stage head ----------------
__global__ __launch_bounds__(128) void head_kernel(
    const float* __restrict__ fused,
    const float* __restrict__ w1, const float* __restrict__ b1,
    const float* __restrict__ gam, const float* __restrict__ bet,
    const float* __restrict__ w2, const float* __restrict__ b2,
    float* __restrict__ logits)
{
  int b = blockIdx.x;
  __shared__ float fl[1024];
  __shared__ float h1[512];
  __shared__ float rs[4];
  for (int k = threadIdx.x; k < 1024; k += 128) fl[k] = fused[b * 1024 + k];
  __syncthreads();
  float vals[4]; float s = 0.f, s2 = 0.f;
  for (int jj = 0; jj < 4; ++jj) {
    int j = threadIdx.x + jj * 128;
    float acc = b1[j];
    const float4* wr = (const float4*)(w1 + (size_t)j * 1024);
    for (int k4 = 0; k4 < 256; ++k4) {
      float4 w = wr[k4];
      acc += w.x * fl[k4 * 4] + w.y * fl[k4 * 4 + 1] + w.z * fl[k4 * 4 + 2] + w.w * fl[k4 * 4 + 3];
    }
    vals[jj] = acc; s += acc; s2 += acc * acc;
  }
  for (int off = 32; off; off >>= 1) { s += __shfl_down(s, off); s2 += __shfl_down(s2, off); }
  int wid = threadIdx.x >> 6;
  if ((threadIdx.x & 63) == 0) { rs[wid] = s; rs[2 + wid] = s2; }
  __syncthreads();
  s = rs[0] + rs[1]; s2 = rs[2] + rs[3];
  float mu = s / 512.f, var = s2 / 512.f - mu * mu;
  float rstd = rsqrtf(var + 1e-5f);
  for (int jj = 0; jj < 4; ++jj) {
    int j = threadIdx.x + jj * 128;
    h1[j] = fmaxf((vals[jj] - mu) * rstd * gam[j] + bet[j], 0.f);
  }
  __syncthreads();
  if (threadIdx.x < 5) {
    float acc = b2[threadIdx.x];
    for (int k = 0; k < 512; ++k) acc += h1[k] * w2[threadIdx.x * 512 + k];
    logits[b * 5 + threadIdx.x] = acc;
  }
}

// ---------------- memory bank update ----------------
__global__ void scatter_last_kernel(const int* __restrict__ cls,
                                    const int* __restrict__ stage, int* __restrict__ last)
{
  int i = blockIdx.x * 256 + threadIdx.x;
  if (i < NT) {
    int b = i >> 7;
    int p = cls[b] * NS + stage[i];
    atomicMax(&last[p], i);
  }
}

__global__ __launch_bounds__(256) void mem_update_kernel(
    const float* __restrict__ mem_in, const float* __restrict__ raw,
    const int* __restrict__ cnt_in, const int* __restrict__ last,
    float* __restrict__ mem_out, float* __restrict__ cnt_out)
{
  int p = blockIdx.x;
  int cnt = cnt_in[p];
  int li = last[p];
  bool present = li >= 0;
  bool full = cnt >= NM;
  int wp = full ? NM - 1 : cnt;
  const float* newf = raw + (size_t)(li < 0 ? 0 : li) * Dv;
  const float* src = mem_in + (size_t)p * NM * Dv;
  float* dst = mem_out + (size_t)p * NM * Dv;
  for (int idx = threadIdx.x; idx < NM * Dv / 4; idx += 256) {
    int m = idx >> 8;          // 256 float4 per row
    int dq = idx & 255;
    float4 v;
    if (present && full) {
      v = (m < NM - 1) ? *(const float4*)(src + (size_t)(m + 1) * Dv + dq * 4)
                       : *(const float4*)(newf + dq * 4);
    } else if (present) {
      v = (m == wp) ? *(const float4*)(newf + dq * 4)
                    : *(const float4*)(src + (size_t)m * Dv + dq * 4);
    } else {
      v = *(const float4*)(src + (size_t)m * Dv + dq * 4);
    }
    *(float4*)(dst + (size_t)m * Dv + dq * 4) = v;
  }
  if (threadIdx.x == 0)
    cnt_out[p] = (float)(cnt + ((present && !full) ? 1 : 0));
}

// =======================================================================
extern "C" void kernel_launch(void* const* d_in, const int* in_sizes, int n_in,
                              void* d_out, int out_size, void* d_ws, size_t ws_size,
                              hipStream_t stream)
{
  (void)in_sizes; (void)n_in; (void)out_size; (void)ws_size;
  const float* x       = (const float*)d_in[0];
  const int* stage     = (const int*)d_in[1];
  const int* cls       = (const int*)d_in[2];
  const float* enc_w1  = (const float*)d_in[3];
  const float* enc_b1  = (const float*)d_in[4];
  const float* enc_g1  = (const float*)d_in[5];
  const float* enc_bb1 = (const float*)d_in[6];
  const float* enc_w2  = (const float*)d_in[7];
  const float* enc_b2  = (const float*)d_in[8];
  const float* enc_g2  = (const float*)d_in[9];
  const float* enc_bb2 = (const float*)d_in[10];
  const float* qkv_w   = (const float*)d_in[11];
  const float* qkv_b   = (const float*)d_in[12];
  const float* out_w   = (const float*)d_in[13];
  const float* out_b   = (const float*)d_in[14];
  const float* norm_g  = (const float*)d_in[15];
  const float* norm_b  = (const float*)d_in[16];
  const float* Wih0    = (const float*)d_in[17];
  const float* Whh0    = (const float*)d_in[18];
  const float* bih0    = (const float*)d_in[19];
  const float* bhh0    = (const float*)d_in[20];
  const float* Wih1    = (const float*)d_in[21];
  const float* Whh1    = (const float*)d_in[22];
  const float* bih1    = (const float*)d_in[23];
  const float* bhh1    = (const float*)d_in[24];
  const float* head_w1 = (const float*)d_in[25];
  const float* head_b1 = (const float*)d_in[26];
  const float* head_g  = (const float*)d_in[27];
  const float* head_bb = (const float*)d_in[28];
  const float* head_w2 = (const float*)d_in[29];
  const float* head_b2 = (const float*)d_in[30];
  const float* gate_w1 = (const float*)d_in[31];
  const float* gate_b1 = (const float*)d_in[32];
  const float* gate_w2 = (const float*)d_in[33];
  const float* gate_b2 = (const float*)d_in[34];
  const float* mem_in  = (const float*)d_in[35];
  const int* cnt_in    = (const int*)d_in[36];

  float* out = (float*)d_out;
  float* out_fused  = out;                      // 65536
  float* out_raw    = out + 65536;              // 8388608
  float* out_logits = out + 8454144;            // 320
  float* out_mem    = out + 8454464;            // 51200000
  float* out_cnt    = out + 59654464;           // 5000

  // ---- workspace layout (bf16 weights + small state), ~42 MB ----
  char* wsb = (char*)d_ws;
  auto alloc = [&](size_t bytes) { char* p = wsb; wsb += (bytes + 255) & ~(size_t)255; return p; };
  bf16* wq16   = (bf16*)alloc((size_t)3072 * 1024 * 2);
  bf16* wo16   = (bf16*)alloc((size_t)1024 * 1024 * 2);
  bf16* wih0b  = (bf16*)alloc((size_t)4096 * 1024 * 2);
  bf16* whh0b  = (bf16*)alloc((size_t)4096 * 1024 * 2);
  bf16* wih1b  = (bf16*)alloc((size_t)4096 * 1024 * 2);
  bf16* whh1b  = (bf16*)alloc((size_t)4096 * 1024 * 2);
  float* bsum0 = (float*)alloc(4096 * 4);
  float* bsum1 = (float*)alloc(4096 * 4);
  bf16* h0buf  = (bf16*)alloc((size_t)2 * 4 * 16384 * 2);  // [parity][gid]: 4096 u64 each
  bf16* h1buf  = (bf16*)alloc((size_t)2 * 4 * 16384 * 2);
  float* pooled  = (float*)alloc(65536 * 4);
  float* rawmean = (float*)alloc(65536 * 4);
  float* gt1     = (float*)alloc(65536 * 4);
  int* last      = (int*)alloc(5000 * 4);
  int* flags     = (int*)alloc(1024);            // 4 groups x 64 ints

  // ---- large activation scratch inside the new_mem output slot (204.8 MB) ----
  char* orb = (char*)out_mem;
  bf16* qkv16 = (bf16*)(orb + 0);            // 50,331,648 B
  bf16* xgT   = (bf16*)(orb + 67108864);     // 67,108,864 B  [t][b][4096]
  bf16* xpe16 = (bf16*)(orb + 134217728);    // 16,777,216 B
  bf16* o16   = (bf16*)(orb + 150994944);    // 16,777,216 B
  bf16* ao16  = (bf16*)(orb + 167772160);    // 16,777,216 B
  bf16* raw16 = (bf16*)(orb + 184549376);    // 16,777,216 B (ends 201,326,592)
  float* embf = (float*)(orb + 201326592);   //  2,621,440 B (ends 203,948,032)

  // 1) weight conversions + bias sums
  f2b_kernel<<<3072, 256, 0, stream>>>(qkv_w, wq16, 786432);
  f2b_kernel<<<1024, 256, 0, stream>>>(out_w, wo16, 262144);
  f2b_kernel<<<4096, 256, 0, stream>>>(Wih0, wih0b, 1048576);
  f2b_kernel<<<4096, 256, 0, stream>>>(Whh0, whh0b, 1048576);
  f2b_kernel<<<4096, 256, 0, stream>>>(Wih1, wih1b, 1048576);
  f2b_kernel<<<4096, 256, 0, stream>>>(Whh1, whh1b, 1048576);
  add2_kernel<<<16, 256, 0, stream>>>(bih0, bhh0, bsum0, 4096);
  add2_kernel<<<16, 256, 0, stream>>>(bih1, bhh1, bsum1, 4096);

  // 2) encoder: 640-row emb table, then fused add -> xpe16
  emb_kernel<<<Tv * NS, 128, 0, stream>>>(enc_w1, enc_b1, enc_g1, enc_bb1,
                                          enc_w2, enc_b2, enc_g2, enc_bb2, embf);
  addemb_kernel<<<NT, 256, 0, stream>>>(x, stage, embf, xpe16);

  // 3) qkv = xpe @ qkv_w^T + b
  gemm128<<<dim3(NT / 128, 3072 / 128), 256, 0, stream>>>(xpe16, wq16, qkv_b, qkv16,
                                                          NT, 3072, Dv, 0);

  // 4) attention -> o16
  attn_kernel<<<Bv * Hv, 256, 0, stream>>>(qkv16, o16);

  // 5) out projection -> ao16
  gemm128<<<dim3(NT / 128, 1024 / 128), 256, 0, stream>>>(o16, wo16, out_b, ao16,
                                                          NT, Dv, Dv, 0);

  // 6) residual + LN -> raw (d_out) + raw16
  residual_ln_kernel<<<NT, 256, 0, stream>>>(xpe16, ao16, norm_g, norm_b, out_raw, raw16);

  // 7) layer-0 input gates (time-major), then fused 2-layer recurrence
  gemm128<<<dim3(NT / 128, 4096 / 128), 256, 0, stream>>>(raw16, wih0b, bsum0, xgT,
                                                          NT, 4096, Dv, 1);
  hipMemsetAsync(flags, 0, 1024, stream);
  lstm_fused<<<256, 512, 0, stream>>>(whh0b, wih1b, whh1b, xgT, bsum1,
                                      h0buf, h1buf, pooled, flags);

  // 8) raw_mean, gated fusion, head
  rawmean_kernel<<<256, 256, 0, stream>>>(out_raw, rawmean);
  gate1_kernel<<<Bv, 256, 0, stream>>>(pooled, rawmean, gate_w1, gate_b1, gt1);
  gate2_kernel<<<Bv, 256, 0, stream>>>(gt1, pooled, rawmean, gate_w2, gate_b2, out_fused);
  head_kernel<<<Bv, 128, 0, stream>>>(out_fused, head_w1, head_b1, head_g, head_bb,
                                      head_w2, head_b2, out_logits);

  // 9) memory bank update (overwrites the scratch region last)
  hipMemsetAsync(last, 0xFF, 5000 * 4, stream);
  scatter_last_kernel<<<32, 256, 0, stream>>>(cls, stage, last);
  mem_update_kernel<<<NC * NS, 256, 0, stream>>>(mem_in, out_raw, cnt_in, last, out_mem, out_cnt);
}

// Round 12
// 1997.864 us; speedup vs baseline: 1.2152x; 1.2001x over previous
//
#include <hip/hip_runtime.h>
#include <hip/hip_bf16.h>

typedef __bf16 bf16x8 __attribute__((ext_vector_type(8)));
typedef float  f32x4  __attribute__((ext_vector_type(4)));
typedef unsigned long long u64;
using bf16 = __hip_bfloat16;

constexpr int Bv = 64, Tv = 128, Dv = 1024, Hv = 8, HDv = 128;
constexpr int NC = 1000, NS = 5, NM = 10;
constexpr int NT = Bv * Tv;           // 8192 tokens

static __device__ __forceinline__ float sigmoidf_(float x) {
  return 1.f / (1.f + __expf(-x));
}

static __device__ __forceinline__ void gload_lds16(const bf16* g, bf16* l) {
  __builtin_amdgcn_global_load_lds(
      (const __attribute__((address_space(1))) void*)g,
      (__attribute__((address_space(3))) void*)l, 16, 0, 0);
}

// ---------------- m97-structure GEMM: C[M,N] = A[M,K] @ W[N,K]^T + bias -------
__global__ __launch_bounds__(256) void gemm128(
    const bf16* __restrict__ A, const bf16* __restrict__ W,
    const float* __restrict__ bias, bf16* __restrict__ C,
    int M, int N, int K, int transT)
{
  __shared__ bf16 sa[128 * 32];
  __shared__ bf16 sb[128 * 32];
  int wave = threadIdx.x >> 6, lane = threadIdx.x & 63;
  int l15 = lane & 15, lhi = lane >> 4;
  int wr = wave >> 1, wc = wave & 1;
  int row0 = blockIdx.x * 128, col0 = blockIdx.y * 128;
  f32x4 acc[4][4];
#pragma unroll
  for (int m = 0; m < 4; ++m)
#pragma unroll
    for (int n = 0; n < 4; ++n) acc[m][n] = f32x4{0.f, 0.f, 0.f, 0.f};

  int sr = wave * 32 + (lane >> 2);
  int sk = (lane & 3) * 8;
  const bf16* srcA = A + (size_t)(row0 + sr) * K + sk;
  const bf16* srcB = W + (size_t)(col0 + sr) * K + sk;
  bf16* dstA0 = &sa[wave * 1024];
  bf16* dstB0 = &sb[wave * 1024];

  for (int k0 = 0; k0 < K; k0 += 32) {
    __syncthreads();
    gload_lds16(srcA + k0,            dstA0);
    gload_lds16(srcA + 16 * K + k0,   dstA0 + 512);
    gload_lds16(srcB + k0,            dstB0);
    gload_lds16(srcB + 16 * K + k0,   dstB0 + 512);
    __syncthreads();
    bf16x8 af[4], bfr[4];
#pragma unroll
    for (int m = 0; m < 4; ++m)
      af[m] = *reinterpret_cast<const bf16x8*>(&sa[(wr * 64 + m * 16 + l15) * 32 + lhi * 8]);
#pragma unroll
    for (int n = 0; n < 4; ++n)
      bfr[n] = *reinterpret_cast<const bf16x8*>(&sb[(wc * 64 + n * 16 + l15) * 32 + lhi * 8]);
#pragma unroll
    for (int m = 0; m < 4; ++m)
#pragma unroll
      for (int n = 0; n < 4; ++n)
        acc[m][n] = __builtin_amdgcn_mfma_f32_16x16x32_bf16(af[m], bfr[n], acc[m][n], 0, 0, 0);
  }

#pragma unroll
  for (int n = 0; n < 4; ++n) {
    int col = col0 + wc * 64 + n * 16 + l15;
    float bv = bias ? bias[col] : 0.f;
#pragma unroll
    for (int m = 0; m < 4; ++m) {
#pragma unroll
      for (int r = 0; r < 4; ++r) {
        int row = row0 + wr * 64 + m * 16 + lhi * 4 + r;
        int orow = transT ? ((row & (Tv - 1)) * Bv + (row >> 7)) : row;
        C[(size_t)orow * N + col] = __float2bfloat16(acc[m][n][r] + bv);
      }
    }
  }
}

// ---------------- fused weight conversions + bias sums (1 launch) -------------
// float4-task regions: qkv 786432 | out 262144 | Wih0/Whh0/Wih1/Whh1 1048576 ea
// | bsum0 1024 | bsum1 1024.  Grid = 5244928/256 = 20488.
__global__ void convert_all(
    const float* __restrict__ qkv_w, const float* __restrict__ out_w,
    const float* __restrict__ Wih0, const float* __restrict__ Whh0,
    const float* __restrict__ Wih1, const float* __restrict__ Whh1,
    const float* __restrict__ bih0, const float* __restrict__ bhh0,
    const float* __restrict__ bih1, const float* __restrict__ bhh1,
    bf16* __restrict__ wq16, bf16* __restrict__ wo16,
    bf16* __restrict__ wih0b, bf16* __restrict__ whh0b,
    bf16* __restrict__ wih1b, bf16* __restrict__ whh1b,
    float* __restrict__ bsum0, float* __restrict__ bsum1)
{
  long i = (long)blockIdx.x * 256 + threadIdx.x;
  const float* s; bf16* d; long off;
  if (i < 786432)        { s = qkv_w; d = wq16;  off = i; }
  else if (i < 1048576)  { s = out_w; d = wo16;  off = i - 786432; }
  else if (i < 2097152)  { s = Wih0;  d = wih0b; off = i - 1048576; }
  else if (i < 3145728)  { s = Whh0;  d = whh0b; off = i - 2097152; }
  else if (i < 4194304)  { s = Wih1;  d = wih1b; off = i - 3145728; }
  else if (i < 5242880)  { s = Whh1;  d = whh1b; off = i - 4194304; }
  else {
    long k = i - 5242880;
    if (k < 1024) {
      float4 a = ((const float4*)bih0)[k], b = ((const float4*)bhh0)[k];
      ((float4*)bsum0)[k] = make_float4(a.x + b.x, a.y + b.y, a.z + b.z, a.w + b.w);
    } else if (k < 2048) {
      k -= 1024;
      float4 a = ((const float4*)bih1)[k], b = ((const float4*)bhh1)[k];
      ((float4*)bsum1)[k] = make_float4(a.x + b.x, a.y + b.y, a.z + b.z, a.w + b.w);
    }
    return;
  }
  float4 v = ((const float4*)s)[off];
  bf16* o = d + off * 4;
  o[0] = __float2bfloat16(v.x); o[1] = __float2bfloat16(v.y);
  o[2] = __float2bfloat16(v.z); o[3] = __float2bfloat16(v.w);
}

// ---------------- emb table: 640 distinct (t, stage) rows ----------------
__global__ __launch_bounds__(128) void emb_kernel(
    const float* __restrict__ w1, const float* __restrict__ b1,
    const float* __restrict__ g1, const float* __restrict__ bb1,
    const float* __restrict__ w2, const float* __restrict__ b2,
    const float* __restrict__ g2, const float* __restrict__ bb2,
    float* __restrict__ emb)
{
  int combo = blockIdx.x;                 // t*5 + s
  float tpos = (float)(combo / 5);
  float stg  = (float)(combo % 5);
  int tid = threadIdx.x;
  __shared__ float hb[64];
  __shared__ float rs[4];
  if (tid < 64) {
    float v = w1[tid * 2] * tpos + w1[tid * 2 + 1] * stg + b1[tid];
    float s = v, s2 = v * v;
    for (int off = 32; off; off >>= 1) { s += __shfl_down(s, off); s2 += __shfl_down(s2, off); }
    s = __shfl(s, 0); s2 = __shfl(s2, 0);
    float mu = s / 64.f, var = s2 / 64.f - mu * mu;
    float h = (v - mu) * rsqrtf(var + 1e-5f) * g1[tid] + bb1[tid];
    hb[tid] = fmaxf(h, 0.f);
  }
  __syncthreads();
  float outv[8];
  float s = 0.f, s2 = 0.f;
  int d0 = tid * 8;
#pragma unroll
  for (int o = 0; o < 8; ++o) {
    int d = d0 + o;
    float acc = b2[d];
    const float4* wr = (const float4*)(w2 + (size_t)d * 64);
#pragma unroll
    for (int k4 = 0; k4 < 16; ++k4) {
      float4 w = wr[k4];
      acc += w.x * hb[k4 * 4] + w.y * hb[k4 * 4 + 1] + w.z * hb[k4 * 4 + 2] + w.w * hb[k4 * 4 + 3];
    }
    outv[o] = acc; s += acc; s2 += acc * acc;
  }
  for (int off = 32; off; off >>= 1) { s += __shfl_down(s, off); s2 += __shfl_down(s2, off); }
  int wid = tid >> 6;
  if ((tid & 63) == 0) { rs[wid] = s; rs[2 + wid] = s2; }
  __syncthreads();
  s = rs[0] + rs[1]; s2 = rs[2] + rs[3];
  float mu = s / 1024.f, var = s2 / 1024.f - mu * mu;
  float rstd = rsqrtf(var + 1e-5f);
  float* op = emb + (size_t)combo * Dv + d0;
#pragma unroll
  for (int o = 0; o < 8; ++o) {
    int d = d0 + o;
    op[o] = (outv[o] - mu) * rstd * g2[d] + bb2[d];
  }
}

__global__ __launch_bounds__(256) void addemb_kernel(
    const float* __restrict__ x, const int* __restrict__ stage,
    const float* __restrict__ emb, bf16* __restrict__ xpe)
{
  int tok = blockIdx.x;
  int row = (tok & (Tv - 1)) * NS + stage[tok];
  const float4* xr = (const float4*)(x + (size_t)tok * Dv);
  const float4* er = (const float4*)(emb + (size_t)row * Dv);
  bf16* op = xpe + (size_t)tok * Dv + threadIdx.x * 4;
  float4 xv = xr[threadIdx.x], ev = er[threadIdx.x];
  op[0] = __float2bfloat16(xv.x + ev.x);
  op[1] = __float2bfloat16(xv.y + ev.y);
  op[2] = __float2bfloat16(xv.z + ev.z);
  op[3] = __float2bfloat16(xv.w + ev.w);
}

// ---------------- attention: per (b,h) flash-style, scalar fp32 ----------------
__global__ __launch_bounds__(256) void attn_kernel(const bf16* __restrict__ qkv,
                                                   bf16* __restrict__ o)
{
  __shared__ bf16 kl[128][128];
  __shared__ bf16 vl[128][128];
  int bh = blockIdx.x;
  int b = bh >> 3, h = bh & 7;
  int tid = threadIdx.x;
  int row = tid >> 1, hf = tid & 1;
  {
    const bf16* ks = qkv + (size_t)(b * Tv + row) * 3072 + Dv + h * HDv + hf * 64;
    const bf16* vs = ks + Dv;
    uint4* dk = (uint4*)&kl[row][hf * 64];
    uint4* dv = (uint4*)&vl[row][hf * 64];
    const uint4* sk = (const uint4*)ks;
    const uint4* sv = (const uint4*)vs;
#pragma unroll
    for (int i = 0; i < 8; ++i) { dk[i] = sk[i]; dv[i] = sv[i]; }
  }
  float qf[64];
  {
    const bf16* qs = qkv + (size_t)(b * Tv + row) * 3072 + h * HDv + hf * 64;
#pragma unroll
    for (int d2 = 0; d2 < 32; ++d2) {
      float2 f = __bfloat1622float2(*(const __hip_bfloat162*)(qs + 2 * d2));
      qf[2 * d2] = f.x; qf[2 * d2 + 1] = f.y;
    }
  }
  __syncthreads();
  float oacc[64];
#pragma unroll
  for (int d = 0; d < 64; ++d) oacc[d] = 0.f;
  float m = -1e30f, l = 0.f;
  const float scale = 0.088388347648318447f;  // 1/sqrt(128)
  for (int j = 0; j < 128; ++j) {
    float part = 0.f;
#pragma unroll
    for (int d2 = 0; d2 < 32; ++d2) {
      float2 kv2 = __bfloat1622float2(*(const __hip_bfloat162*)&kl[j][hf * 64 + 2 * d2]);
      part += qf[2 * d2] * kv2.x + qf[2 * d2 + 1] * kv2.y;
    }
    float sfull = (part + __shfl_xor(part, 1)) * scale;
    float mn = fmaxf(m, sfull);
    float al = __expf(m - mn);
    float p = __expf(sfull - mn);
    l = l * al + p;
#pragma unroll
    for (int d2 = 0; d2 < 32; ++d2) {
      float2 vv = __bfloat1622float2(*(const __hip_bfloat162*)&vl[j][hf * 64 + 2 * d2]);
      oacc[2 * d2]     = oacc[2 * d2] * al + p * vv.x;
      oacc[2 * d2 + 1] = oacc[2 * d2 + 1] * al + p * vv.y;
    }
    m = mn;
  }
  float rl = 1.f / l;
  bf16* od = o + (size_t)(b * Tv + row) * Dv + h * HDv + hf * 64;
#pragma unroll
  for (int d = 0; d < 64; ++d) od[d] = __float2bfloat16(oacc[d] * rl);
}

// ---------------- residual + LN -> raw (f32 to d_out) + raw16 -----------------
__global__ __launch_bounds__(256) void residual_ln_kernel(
    const bf16* __restrict__ xpe, const bf16* __restrict__ ao,
    const float* __restrict__ gam, const float* __restrict__ bet,
    float* __restrict__ rawf, bf16* __restrict__ raw16)
{
  int tok = blockIdx.x, tid = threadIdx.x;
  float v[4]; float s = 0.f, s2 = 0.f;
  __shared__ float rs[8];
#pragma unroll
  for (int q = 0; q < 4; ++q) {
    int d = tid + q * 256;
    size_t idx = (size_t)tok * Dv + d;
    float a = __bfloat162float(xpe[idx]) + __bfloat162float(ao[idx]);
    v[q] = a; s += a; s2 += a * a;
  }
  for (int off = 32; off; off >>= 1) { s += __shfl_down(s, off); s2 += __shfl_down(s2, off); }
  int wid = tid >> 6;
  if ((tid & 63) == 0) { rs[wid] = s; rs[4 + wid] = s2; }
  __syncthreads();
  s = rs[0] + rs[1] + rs[2] + rs[3];
  s2 = rs[4] + rs[5] + rs[6] + rs[7];
  float mu = s / 1024.f, var = s2 / 1024.f - mu * mu;
  float rstd = rsqrtf(var + 1e-5f);
#pragma unroll
  for (int q = 0; q < 4; ++q) {
    int d = tid + q * 256;
    size_t idx = (size_t)tok * Dv + d;
    float rv = (v[q] - mu) * rstd * gam[d] + bet[d];
    rawf[idx] = rv;
    raw16[idx] = __float2bfloat16(rv);
  }
}

// ---------------- fused 2-layer pipelined persistent LSTM (r9 verbatim) -------
// Grid 256 x 512 (8 waves: gate g = wave&3, K-half kh = wave>>2).
// Block (gid, j): batches gid*16..+15, units j*16..+15, both layers.
// Weights stream from L2 (r9's measured optimum: 1011 us; all register-
// residency attempts r9-r11 were neutral-to-worse). K-half partials combined
// through LDS. Exchange/barrier: h0/h1 [parity][gid][j][64 u64], sc1 ops;
// flags[gid][64] = completed super-steps.
__global__ __launch_bounds__(512, 1) void lstm_fused(
    const bf16* __restrict__ Whh0, const bf16* __restrict__ Wih1,
    const bf16* __restrict__ Whh1, const bf16* __restrict__ xgT,
    const float* __restrict__ bsum1,
    bf16* h0buf, bf16* h1buf,
    float* __restrict__ pooled, int* flags)
{
  const int bid = blockIdx.x;
  const int xcd = bid & 7, idx = bid >> 3;
  const int j   = xcd * 8 + (idx & 7);   // unit block 0..63
  const int gid = idx >> 3;              // batch group 0..3
  const int u0  = j * 16;
  const int tid = threadIdx.x;
  const int wave = tid >> 6, lane = tid & 63;
  const int g = wave & 3, kh = wave >> 2;
  const int l15 = lane & 15, lhi = lane >> 4;
  const int koff = lhi * 8;

  // register-resident weight slices (rows g*Dv+u0+l15, K-half kh)
  bf16x8 w0h[16], w1h[16], wh1h[16];
  {
    const size_t rowoff = (size_t)(g * Dv + u0 + l15) * Dv + kh * 512 + koff;
    const bf16* r0 = Whh0 + rowoff;
    const bf16* r1 = Wih1 + rowoff;
    const bf16* r2 = Whh1 + rowoff;
#pragma unroll
    for (int i = 0; i < 16; ++i) {
      w0h[i]  = *reinterpret_cast<const bf16x8*>(r0 + i * 32);
      w1h[i]  = *reinterpret_cast<const bf16x8*>(r1 + i * 32);
      wh1h[i] = *reinterpret_cast<const bf16x8*>(r2 + i * 32);
    }
#pragma unroll
    for (int i = 0; i < 16; ++i) {
      asm volatile("" : "+v"(w0h[i]));
      asm volatile("" : "+v"(w1h[i]));
      asm volatile("" : "+v"(wh1h[i]));
    }
  }
  const float bs1 = bsum1[g * Dv + u0 + l15];

  __shared__ bf16 hA[16 * 2056];       // [batch][0..1023 h0 | 1024..2047 h1 | pad]
  __shared__ float gl0[2][4][16][16];  // [kh][gate][batch][unit]
  __shared__ float gl1[2][4][16][16];
  __shared__ bf16 hst0[256];
  __shared__ bf16 hst1[256];

  const int bb_t = (tid & 255) >> 4, uu_t = tid & 15;
  float c0 = 0.f, c1 = 0.f;
  int* gflags = flags + gid * 64;

  for (int s = 0; s <= Tv; ++s) {
    // ---- xg prefetch for L0 t=s (kh==0 waves carry it) ----
    float xv[4] = {0.f, 0.f, 0.f, 0.f};
    if (s < Tv && kh == 0) {
      const bf16* xg_t = xgT + (size_t)s * (Bv * 4 * Dv)
                         + (size_t)(gid * 16) * (4 * Dv) + g * Dv + u0 + l15;
#pragma unroll
      for (int r = 0; r < 4; ++r)
        xv[r] = __bfloat162float(xg_t[(size_t)(lhi * 4 + r) * (4 * Dv)]);
    }
    // ---- barrier: all 64 group flags >= s ----
    if (s > 0) {
      if (tid < 64) {
        while (true) {
          int v = __hip_atomic_load(gflags + tid, __ATOMIC_RELAXED, __HIP_MEMORY_SCOPE_AGENT);
          if (__all(v >= s)) break;
          __builtin_amdgcn_s_sleep(1);
        }
      }
      __syncthreads();                                   // S1
      // ---- stage h0(s-1) + h1(s-2) into LDS (sc1 loads) ----
      {
        const u64* s0 = (const u64*)h0buf + (size_t)(((s - 1) & 1) * 4 + gid) * 4096;
        u64* dA = (u64*)hA;
#pragma unroll
        for (int it = 0; it < 8; ++it) {
          int id = it * 512 + tid;
          int jc = id >> 6, r = id & 63, bb = r >> 2, uq = r & 3;
          u64 v = __hip_atomic_load(s0 + id, __ATOMIC_RELAXED, __HIP_MEMORY_SCOPE_AGENT);
          dA[bb * 514 + jc * 4 + uq] = v;
        }
        if (s >= 2) {
          const u64* s1 = (const u64*)h1buf + (size_t)(((s - 2) & 1) * 4 + gid) * 4096;
#pragma unroll
          for (int it = 0; it < 8; ++it) {
            int id = it * 512 + tid;
            int jc = id >> 6, r = id & 63, bb = r >> 2, uq = r & 3;
            u64 v = __hip_atomic_load(s1 + id, __ATOMIC_RELAXED, __HIP_MEMORY_SCOPE_AGENT);
            dA[bb * 514 + 256 + jc * 4 + uq] = v;
          }
        }
      }
      __syncthreads();                                   // S2
    }

    // ================= layer 0: t = s (K-half partial) =================
    if (s < Tv) {
      f32x4 acc = f32x4{0.f, 0.f, 0.f, 0.f};
      if (s > 0) {
#pragma unroll
        for (int i = 0; i < 16; ++i) {
          bf16x8 a = *reinterpret_cast<const bf16x8*>(&hA[l15 * 2056 + kh * 512 + i * 32 + koff]);
          acc = __builtin_amdgcn_mfma_f32_16x16x32_bf16(a, w0h[i], acc, 0, 0, 0);
        }
      }
#pragma unroll
      for (int r = 0; r < 4; ++r)
        gl0[kh][g][lhi * 4 + r][l15] = acc[r] + xv[r];
    }
    // ================= layer 1: t = s-1 (K-half partial) =================
    if (s > 0) {
      f32x4 acc = f32x4{0.f, 0.f, 0.f, 0.f};
#pragma unroll
      for (int i = 0; i < 16; ++i) {                     // y0 term (Wih1)
        bf16x8 a = *reinterpret_cast<const bf16x8*>(&hA[l15 * 2056 + kh * 512 + i * 32 + koff]);
        acc = __builtin_amdgcn_mfma_f32_16x16x32_bf16(a, w1h[i], acc, 0, 0, 0);
      }
      if (s >= 2) {
#pragma unroll
        for (int i = 0; i < 16; ++i) {                   // h1 term (Whh1)
          bf16x8 a = *reinterpret_cast<const bf16x8*>(&hA[l15 * 2056 + 1024 + kh * 512 + i * 32 + koff]);
          acc = __builtin_amdgcn_mfma_f32_16x16x32_bf16(a, wh1h[i], acc, 0, 0, 0);
        }
      }
#pragma unroll
      for (int r = 0; r < 4; ++r)
        gl1[kh][g][lhi * 4 + r][l15] = acc[r] + (kh == 0 ? bs1 : 0.f);
    }
    __syncthreads();                                     // S3
    // ---- gates: combine K-halves, nonlinearity, c/h update ----
    if (tid < 256) {
      if (s < Tv) {
        float gi = gl0[0][0][bb_t][uu_t] + gl0[1][0][bb_t][uu_t];
        float gf = gl0[0][1][bb_t][uu_t] + gl0[1][1][bb_t][uu_t];
        float gc = gl0[0][2][bb_t][uu_t] + gl0[1][2][bb_t][uu_t];
        float go = gl0[0][3][bb_t][uu_t] + gl0[1][3][bb_t][uu_t];
        float cn = sigmoidf_(gf) * c0 + sigmoidf_(gi) * tanhf(gc);
        float hn = sigmoidf_(go) * tanhf(cn);
        c0 = cn;
        hst0[bb_t * 16 + uu_t] = __float2bfloat16(hn);
      }
      if (s > 0) {
        float gi = gl1[0][0][bb_t][uu_t] + gl1[1][0][bb_t][uu_t];
        float gf = gl1[0][1][bb_t][uu_t] + gl1[1][1][bb_t][uu_t];
        float gc = gl1[0][2][bb_t][uu_t] + gl1[1][2][bb_t][uu_t];
        float go = gl1[0][3][bb_t][uu_t] + gl1[1][3][bb_t][uu_t];
        float cn = sigmoidf_(gf) * c1 + sigmoidf_(gi) * tanhf(gc);
        float hn = sigmoidf_(go) * tanhf(cn);
        c1 = cn;
        hst1[bb_t * 16 + uu_t] = __float2bfloat16(hn);
        if (s == Tv) pooled[(gid * 16 + bb_t) * Dv + u0 + uu_t] = hn;
      }
    }
    __syncthreads();                                     // S4
    // ---- sc1 stores of h chunks ----
    if (s < Tv && tid < 64) {
      u64* dst = (u64*)h0buf + (size_t)((s & 1) * 4 + gid) * 4096 + j * 64 + tid;
      __hip_atomic_store(dst, ((u64*)hst0)[tid], __ATOMIC_RELAXED, __HIP_MEMORY_SCOPE_AGENT);
    }
    if (s > 0 && tid >= 64 && tid < 128) {
      int q = tid - 64;
      u64* dst = (u64*)h1buf + (size_t)(((s - 1) & 1) * 4 + gid) * 4096 + j * 64 + q;
      __hip_atomic_store(dst, ((u64*)hst1)[q], __ATOMIC_RELAXED, __HIP_MEMORY_SCOPE_AGENT);
    }
    // ---- drain + flag ----
    if (s < Tv) {
      asm volatile("s_waitcnt vmcnt(0)" ::: "memory");
      __syncthreads();                                   // S5
      if (tid == 0)
        __hip_atomic_store(gflags + j, s + 1, __ATOMIC_RELAXED, __HIP_MEMORY_SCOPE_AGENT);
    }
  }
}

// ---------------- raw_mean over T ----------------
__global__ void rawmean_kernel(const float* __restrict__ raw, float* __restrict__ out)
{
  int i = blockIdx.x * 256 + threadIdx.x;   // 65536
  int b = i >> 10, d = i & 1023;
  const float* r = raw + (size_t)b * Tv * Dv + d;
  float s = 0.f;
  for (int t = 0; t < Tv; ++t) s += r[(size_t)t * Dv];
  out[i] = s * (1.f / Tv);
}

// ---------------- fused gated-fusion + stage head (per batch) -----------------
// gate1 -> gate2 -> fused -> head LN -> logits, all in LDS. Per-(b,j) inner
// k-summation order identical to the previous 3 kernels.
__global__ __launch_bounds__(256) void gatehead_kernel(
    const float* __restrict__ pooled, const float* __restrict__ rawmean,
    const float* __restrict__ gw1, const float* __restrict__ gb1,
    const float* __restrict__ gw2, const float* __restrict__ gb2,
    const float* __restrict__ hw1, const float* __restrict__ hb1,
    const float* __restrict__ hg, const float* __restrict__ hbb,
    const float* __restrict__ hw2, const float* __restrict__ hb2,
    float* __restrict__ fused_out, float* __restrict__ logits)
{
  int b = blockIdx.x, tid = threadIdx.x;
  __shared__ float cat[2048];
  __shared__ float g1v[1024];
  __shared__ float fl[1024];
  __shared__ float h1[512];
  __shared__ float rs[8];
  for (int k = tid; k < 1024; k += 256) {
    cat[k] = pooled[b * 1024 + k];
    cat[1024 + k] = rawmean[b * 1024 + k];
  }
  __syncthreads();
  // gate1 (relu)
  for (int jj = 0; jj < 4; ++jj) {
    int j = tid + jj * 256;
    float acc = gb1[j];
    const float4* wr = (const float4*)(gw1 + (size_t)j * 2048);
    for (int k4 = 0; k4 < 512; ++k4) {
      float4 w = wr[k4];
      acc += w.x * cat[k4 * 4] + w.y * cat[k4 * 4 + 1] + w.z * cat[k4 * 4 + 2] + w.w * cat[k4 * 4 + 3];
    }
    g1v[j] = fmaxf(acc, 0.f);
  }
  __syncthreads();
  // gate2 (sigmoid) + fused mix
  for (int jj = 0; jj < 4; ++jj) {
    int j = tid + jj * 256;
    float acc = gb2[j];
    const float4* wr = (const float4*)(gw2 + (size_t)j * 1024);
    for (int k4 = 0; k4 < 256; ++k4) {
      float4 w = wr[k4];
      acc += w.x * g1v[k4 * 4] + w.y * g1v[k4 * 4 + 1] + w.z * g1v[k4 * 4 + 2] + w.w * g1v[k4 * 4 + 3];
    }
    float gv = sigmoidf_(acc);
    float f = gv * cat[j] + (1.f - gv) * cat[1024 + j];
    fused_out[b * 1024 + j] = f;
    fl[j] = f;
  }
  __syncthreads();
  // head: 512 hidden (2 per thread), LN, relu, logits
  float v0, v1;
  {
    float acc = hb1[tid];
    const float4* wr = (const float4*)(hw1 + (size_t)tid * 1024);
    for (int k4 = 0; k4 < 256; ++k4) {
      float4 w = wr[k4];
      acc += w.x * fl[k4 * 4] + w.y * fl[k4 * 4 + 1] + w.z * fl[k4 * 4 + 2] + w.w * fl[k4 * 4 + 3];
    }
    v0 = acc;
    acc = hb1[tid + 256];
    wr = (const float4*)(hw1 + (size_t)(tid + 256) * 1024);
    for (int k4 = 0; k4 < 256; ++k4) {
      float4 w = wr[k4];
      acc += w.x * fl[k4 * 4] + w.y * fl[k4 * 4 + 1] + w.z * fl[k4 * 4 + 2] + w.w * fl[k4 * 4 + 3];
    }
    v1 = acc;
  }
  float s = v0 + v1, s2 = v0 * v0 + v1 * v1;
  for (int off = 32; off; off >>= 1) { s += __shfl_down(s, off); s2 += __shfl_down(s2, off); }
  int wid = tid >> 6;
  if ((tid & 63) == 0) { rs[wid] = s; rs[4 + wid] = s2; }
  __syncthreads();
  s = rs[0] + rs[1] + rs[2] + rs[3];
  s2 = rs[4] + rs[5] + rs[6] + rs[7];
  float mu = s / 512.f, var = s2 / 512.f - mu * mu;
  float rstd = rsqrtf(var + 1e-5f);
  h1[tid]       = fmaxf((v0 - mu) * rstd * hg[tid] + hbb[tid], 0.f);
  h1[tid + 256] = fmaxf((v1 - mu) * rstd * hg[tid + 256] + hbb[tid + 256], 0.f);
  __syncthreads();
  if (tid < 5) {
    float acc = hb2[tid];
    for (int k = 0; k < 512; ++k) acc += h1[k] * hw2[tid * 512 + k];
    logits[b * 5 + tid] = acc;
  }
}

// ---------------- memory bank update ----------------
__global__ void scatter_last_kernel(const int* __restrict__ cls,
                                    const int* __restrict__ stage, int* __restrict__ last)
{
  int i = blockIdx.x * 256 + threadIdx.x;
  if (i < NT) {
    int b = i >> 7;
    int p = cls[b] * NS + stage[i];
    atomicMax(&last[p], i);
  }
}

__global__ __launch_bounds__(256) void mem_update_kernel(
    const float* __restrict__ mem_in, const float* __restrict__ raw,
    const int* __restrict__ cnt_in, const int* __restrict__ last,
    float* __restrict__ mem_out, float* __restrict__ cnt_out)
{
  int p = blockIdx.x;
  int cnt = cnt_in[p];
  int li = last[p];
  bool present = li >= 0;
  bool full = cnt >= NM;
  int wp = full ? NM - 1 : cnt;
  const float* newf = raw + (size_t)(li < 0 ? 0 : li) * Dv;
  const float* src = mem_in + (size_t)p * NM * Dv;
  float* dst = mem_out + (size_t)p * NM * Dv;
  for (int idx = threadIdx.x; idx < NM * Dv / 4; idx += 256) {
    int m = idx >> 8;          // 256 float4 per row
    int dq = idx & 255;
    float4 v;
    if (present && full) {
      v = (m < NM - 1) ? *(const float4*)(src + (size_t)(m + 1) * Dv + dq * 4)
                       : *(const float4*)(newf + dq * 4);
    } else if (present) {
      v = (m == wp) ? *(const float4*)(newf + dq * 4)
                    : *(const float4*)(src + (size_t)m * Dv + dq * 4);
    } else {
      v = *(const float4*)(src + (size_t)m * Dv + dq * 4);
    }
    *(float4*)(dst + (size_t)m * Dv + dq * 4) = v;
  }
  if (threadIdx.x == 0)
    cnt_out[p] = (float)(cnt + ((present && !full) ? 1 : 0));
}

// =======================================================================
extern "C" void kernel_launch(void* const* d_in, const int* in_sizes, int n_in,
                              void* d_out, int out_size, void* d_ws, size_t ws_size,
                              hipStream_t stream)
{
  (void)in_sizes; (void)n_in; (void)out_size; (void)ws_size;
  const float* x       = (const float*)d_in[0];
  const int* stage     = (const int*)d_in[1];
  const int* cls       = (const int*)d_in[2];
  const float* enc_w1  = (const float*)d_in[3];
  const float* enc_b1  = (const float*)d_in[4];
  const float* enc_g1  = (const float*)d_in[5];
  const float* enc_bb1 = (const float*)d_in[6];
  const float* enc_w2  = (const float*)d_in[7];
  const float* enc_b2  = (const float*)d_in[8];
  const float* enc_g2  = (const float*)d_in[9];
  const float* enc_bb2 = (const float*)d_in[10];
  const float* qkv_w   = (const float*)d_in[11];
  const float* qkv_b   = (const float*)d_in[12];
  const float* out_w   = (const float*)d_in[13];
  const float* out_b   = (const float*)d_in[14];
  const float* norm_g  = (const float*)d_in[15];
  const float* norm_b  = (const float*)d_in[16];
  const float* Wih0    = (const float*)d_in[17];
  const float* Whh0    = (const float*)d_in[18];
  const float* bih0    = (const float*)d_in[19];
  const float* bhh0    = (const float*)d_in[20];
  const float* Wih1    = (const float*)d_in[21];
  const float* Whh1    = (const float*)d_in[22];
  const float* bih1    = (const float*)d_in[23];
  const float* bhh1    = (const float*)d_in[24];
  const float* head_w1 = (const float*)d_in[25];
  const float* head_b1 = (const float*)d_in[26];
  const float* head_g  = (const float*)d_in[27];
  const float* head_bb = (const float*)d_in[28];
  const float* head_w2 = (const float*)d_in[29];
  const float* head_b2 = (const float*)d_in[30];
  const float* gate_w1 = (const float*)d_in[31];
  const float* gate_b1 = (const float*)d_in[32];
  const float* gate_w2 = (const float*)d_in[33];
  const float* gate_b2 = (const float*)d_in[34];
  const float* mem_in  = (const float*)d_in[35];
  const int* cnt_in    = (const int*)d_in[36];

  float* out = (float*)d_out;
  float* out_fused  = out;                      // 65536
  float* out_raw    = out + 65536;              // 8388608
  float* out_logits = out + 8454144;            // 320
  float* out_mem    = out + 8454464;            // 51200000
  float* out_cnt    = out + 59654464;           // 5000

  // ---- workspace layout (bf16 weights + small state), ~42 MB ----
  char* wsb = (char*)d_ws;
  auto alloc = [&](size_t bytes) { char* p = wsb; wsb += (bytes + 255) & ~(size_t)255; return p; };
  bf16* wq16   = (bf16*)alloc((size_t)3072 * 1024 * 2);
  bf16* wo16   = (bf16*)alloc((size_t)1024 * 1024 * 2);
  bf16* wih0b  = (bf16*)alloc((size_t)4096 * 1024 * 2);
  bf16* whh0b  = (bf16*)alloc((size_t)4096 * 1024 * 2);
  bf16* wih1b  = (bf16*)alloc((size_t)4096 * 1024 * 2);
  bf16* whh1b  = (bf16*)alloc((size_t)4096 * 1024 * 2);
  float* bsum0 = (float*)alloc(4096 * 4);
  float* bsum1 = (float*)alloc(4096 * 4);
  bf16* h0buf  = (bf16*)alloc((size_t)2 * 4 * 16384 * 2);  // [parity][gid]: 4096 u64 each
  bf16* h1buf  = (bf16*)alloc((size_t)2 * 4 * 16384 * 2);
  float* pooled  = (float*)alloc(65536 * 4);
  float* rawmean = (float*)alloc(65536 * 4);
  int* last      = (int*)alloc(5000 * 4);
  int* flags     = (int*)alloc(1024);            // 4 groups x 64 ints

  // ---- large activation scratch inside the new_mem output slot (204.8 MB) ----
  char* orb = (char*)out_mem;
  bf16* qkv16 = (bf16*)(orb + 0);            // 50,331,648 B
  bf16* xgT   = (bf16*)(orb + 67108864);     // 67,108,864 B  [t][b][4096]
  bf16* xpe16 = (bf16*)(orb + 134217728);    // 16,777,216 B
  bf16* o16   = (bf16*)(orb + 150994944);    // 16,777,216 B
  bf16* ao16  = (bf16*)(orb + 167772160);    // 16,777,216 B
  bf16* raw16 = (bf16*)(orb + 184549376);    // 16,777,216 B (ends 201,326,592)
  float* embf = (float*)(orb + 201326592);   //  2,621,440 B (ends 203,948,032)

  // 1) fused weight conversions + bias sums (single launch)
  convert_all<<<20488, 256, 0, stream>>>(qkv_w, out_w, Wih0, Whh0, Wih1, Whh1,
                                         bih0, bhh0, bih1, bhh1,
                                         wq16, wo16, wih0b, whh0b, wih1b, whh1b,
                                         bsum0, bsum1);

  // 2) encoder: 640-row emb table, then fused add -> xpe16
  emb_kernel<<<Tv * NS, 128, 0, stream>>>(enc_w1, enc_b1, enc_g1, enc_bb1,
                                          enc_w2, enc_b2, enc_g2, enc_bb2, embf);
  addemb_kernel<<<NT, 256, 0, stream>>>(x, stage, embf, xpe16);

  // 3) qkv = xpe @ qkv_w^T + b
  gemm128<<<dim3(NT / 128, 3072 / 128), 256, 0, stream>>>(xpe16, wq16, qkv_b, qkv16,
                                                          NT, 3072, Dv, 0);

  // 4) attention -> o16
  attn_kernel<<<Bv * Hv, 256, 0, stream>>>(qkv16, o16);

  // 5) out projection -> ao16
  gemm128<<<dim3(NT / 128, 1024 / 128), 256, 0, stream>>>(o16, wo16, out_b, ao16,
                                                          NT, Dv, Dv, 0);

  // 6) residual + LN -> raw (d_out) + raw16
  residual_ln_kernel<<<NT, 256, 0, stream>>>(xpe16, ao16, norm_g, norm_b, out_raw, raw16);

  // 7) layer-0 input gates (time-major), then fused 2-layer recurrence
  gemm128<<<dim3(NT / 128, 4096 / 128), 256, 0, stream>>>(raw16, wih0b, bsum0, xgT,
                                                          NT, 4096, Dv, 1);
  hipMemsetAsync(flags, 0, 1024, stream);
  lstm_fused<<<256, 512, 0, stream>>>(whh0b, wih1b, whh1b, xgT, bsum1,
                                      h0buf, h1buf, pooled, flags);

  // 8) raw_mean, fused gate+head
  rawmean_kernel<<<256, 256, 0, stream>>>(out_raw, rawmean);
  gatehead_kernel<<<Bv, 256, 0, stream>>>(pooled, rawmean,
                                          gate_w1, gate_b1, gate_w2, gate_b2,
                                          head_w1, head_b1, head_g, head_bb,
                                          head_w2, head_b2, out_fused, out_logits);

  // 9) memory bank update (overwrites the scratch region last)
  hipMemsetAsync(last, 0xFF, 5000 * 4, stream);
  scatter_last_kernel<<<32, 256, 0, stream>>>(cls, stage, last);
  mem_update_kernel<<<NC * NS, 256, 0, stream>>>(mem_in, out_raw, cnt_in, last, out_mem, out_cnt);
}

// Round 13
// 1854.348 us; speedup vs baseline: 1.3093x; 1.0774x over previous
//
#include <hip/hip_runtime.h>
#include <hip/hip_bf16.h>

typedef __bf16 bf16x8 __attribute__((ext_vector_type(8)));
typedef float  f32x4  __attribute__((ext_vector_type(4)));
typedef unsigned long long u64;
using bf16 = __hip_bfloat16;

constexpr int Bv = 64, Tv = 128, Dv = 1024, Hv = 8, HDv = 128;
constexpr int NC = 1000, NS = 5, NM = 10;
constexpr int NT = Bv * Tv;           // 8192 tokens

static __device__ __forceinline__ float sigmoidf_(float x) {
  return 1.f / (1.f + __expf(-x));
}

static __device__ __forceinline__ void gload_lds16(const bf16* g, bf16* l) {
  __builtin_amdgcn_global_load_lds(
      (const __attribute__((address_space(1))) void*)g,
      (__attribute__((address_space(3))) void*)l, 16, 0, 0);
}

// dot of 8 bf16 (as uint4) with 8 f32 from LDS
static __device__ __forceinline__ float dot8(uint4 w8, const float* c) {
  union { uint4 u; __hip_bfloat162 h[4]; } W; W.u = w8;
  float acc = 0.f;
#pragma unroll
  for (int e = 0; e < 4; ++e) {
    float2 f = __bfloat1622float2(W.h[e]);
    acc += f.x * c[2 * e] + f.y * c[2 * e + 1];
  }
  return acc;
}

// ---------------- m97-structure GEMM: C[M,N] = A[M,K] @ W[N,K]^T + bias -------
__global__ __launch_bounds__(256) void gemm128(
    const bf16* __restrict__ A, const bf16* __restrict__ W,
    const float* __restrict__ bias, bf16* __restrict__ C,
    int M, int N, int K, int transT)
{
  __shared__ bf16 sa[128 * 32];
  __shared__ bf16 sb[128 * 32];
  int wave = threadIdx.x >> 6, lane = threadIdx.x & 63;
  int l15 = lane & 15, lhi = lane >> 4;
  int wr = wave >> 1, wc = wave & 1;
  int row0 = blockIdx.x * 128, col0 = blockIdx.y * 128;
  f32x4 acc[4][4];
#pragma unroll
  for (int m = 0; m < 4; ++m)
#pragma unroll
    for (int n = 0; n < 4; ++n) acc[m][n] = f32x4{0.f, 0.f, 0.f, 0.f};

  int sr = wave * 32 + (lane >> 2);
  int sk = (lane & 3) * 8;
  const bf16* srcA = A + (size_t)(row0 + sr) * K + sk;
  const bf16* srcB = W + (size_t)(col0 + sr) * K + sk;
  bf16* dstA0 = &sa[wave * 1024];
  bf16* dstB0 = &sb[wave * 1024];

  for (int k0 = 0; k0 < K; k0 += 32) {
    __syncthreads();
    gload_lds16(srcA + k0,            dstA0);
    gload_lds16(srcA + 16 * K + k0,   dstA0 + 512);
    gload_lds16(srcB + k0,            dstB0);
    gload_lds16(srcB + 16 * K + k0,   dstB0 + 512);
    __syncthreads();
    bf16x8 af[4], bfr[4];
#pragma unroll
    for (int m = 0; m < 4; ++m)
      af[m] = *reinterpret_cast<const bf16x8*>(&sa[(wr * 64 + m * 16 + l15) * 32 + lhi * 8]);
#pragma unroll
    for (int n = 0; n < 4; ++n)
      bfr[n] = *reinterpret_cast<const bf16x8*>(&sb[(wc * 64 + n * 16 + l15) * 32 + lhi * 8]);
#pragma unroll
    for (int m = 0; m < 4; ++m)
#pragma unroll
      for (int n = 0; n < 4; ++n)
        acc[m][n] = __builtin_amdgcn_mfma_f32_16x16x32_bf16(af[m], bfr[n], acc[m][n], 0, 0, 0);
  }

#pragma unroll
  for (int n = 0; n < 4; ++n) {
    int col = col0 + wc * 64 + n * 16 + l15;
    float bv = bias ? bias[col] : 0.f;
#pragma unroll
    for (int m = 0; m < 4; ++m) {
#pragma unroll
      for (int r = 0; r < 4; ++r) {
        int row = row0 + wr * 64 + m * 16 + lhi * 4 + r;
        int orow = transT ? ((row & (Tv - 1)) * Bv + (row >> 7)) : row;
        C[(size_t)orow * N + col] = __float2bfloat16(acc[m][n][r] + bv);
      }
    }
  }
}

// ---------------- fused weight conversions + bias sums (1 launch) -------------
// float4-task regions (in f4 units):
// qkv 786432 | out 262144 | Wih0/Whh0/Wih1/Whh1 1048576 ea | gw1 524288 |
// gw2 262144 | hw1 131072 | bsum0 1024 | bsum1 1024. Grid = 24072.
__global__ void convert_all(
    const float* __restrict__ qkv_w, const float* __restrict__ out_w,
    const float* __restrict__ Wih0, const float* __restrict__ Whh0,
    const float* __restrict__ Wih1, const float* __restrict__ Whh1,
    const float* __restrict__ gw1, const float* __restrict__ gw2,
    const float* __restrict__ hw1,
    const float* __restrict__ bih0, const float* __restrict__ bhh0,
    const float* __restrict__ bih1, const float* __restrict__ bhh1,
    bf16* __restrict__ wq16, bf16* __restrict__ wo16,
    bf16* __restrict__ wih0b, bf16* __restrict__ whh0b,
    bf16* __restrict__ wih1b, bf16* __restrict__ whh1b,
    bf16* __restrict__ gw1b, bf16* __restrict__ gw2b, bf16* __restrict__ hw1b,
    float* __restrict__ bsum0, float* __restrict__ bsum1)
{
  long i = (long)blockIdx.x * 256 + threadIdx.x;
  const float* s; bf16* d; long off;
  if (i < 786432)        { s = qkv_w; d = wq16;  off = i; }
  else if (i < 1048576)  { s = out_w; d = wo16;  off = i - 786432; }
  else if (i < 2097152)  { s = Wih0;  d = wih0b; off = i - 1048576; }
  else if (i < 3145728)  { s = Whh0;  d = whh0b; off = i - 2097152; }
  else if (i < 4194304)  { s = Wih1;  d = wih1b; off = i - 3145728; }
  else if (i < 5242880)  { s = Whh1;  d = whh1b; off = i - 4194304; }
  else if (i < 5767168)  { s = gw1;   d = gw1b;  off = i - 5242880; }
  else if (i < 6029312)  { s = gw2;   d = gw2b;  off = i - 5767168; }
  else if (i < 6160384)  { s = hw1;   d = hw1b;  off = i - 6029312; }
  else {
    long k = i - 6160384;
    if (k < 1024) {
      float4 a = ((const float4*)bih0)[k], b = ((const float4*)bhh0)[k];
      ((float4*)bsum0)[k] = make_float4(a.x + b.x, a.y + b.y, a.z + b.z, a.w + b.w);
    } else if (k < 2048) {
      k -= 1024;
      float4 a = ((const float4*)bih1)[k], b = ((const float4*)bhh1)[k];
      ((float4*)bsum1)[k] = make_float4(a.x + b.x, a.y + b.y, a.z + b.z, a.w + b.w);
    }
    return;
  }
  float4 v = ((const float4*)s)[off];
  bf16* o = d + off * 4;
  o[0] = __float2bfloat16(v.x); o[1] = __float2bfloat16(v.y);
  o[2] = __float2bfloat16(v.z); o[3] = __float2bfloat16(v.w);
}

// ---------------- emb table: 640 distinct (t, stage) rows ----------------
__global__ __launch_bounds__(128) void emb_kernel(
    const float* __restrict__ w1, const float* __restrict__ b1,
    const float* __restrict__ g1, const float* __restrict__ bb1,
    const float* __restrict__ w2, const float* __restrict__ b2,
    const float* __restrict__ g2, const float* __restrict__ bb2,
    float* __restrict__ emb)
{
  int combo = blockIdx.x;                 // t*5 + s
  float tpos = (float)(combo / 5);
  float stg  = (float)(combo % 5);
  int tid = threadIdx.x;
  __shared__ float hb[64];
  __shared__ float rs[4];
  if (tid < 64) {
    float v = w1[tid * 2] * tpos + w1[tid * 2 + 1] * stg + b1[tid];
    float s = v, s2 = v * v;
    for (int off = 32; off; off >>= 1) { s += __shfl_down(s, off); s2 += __shfl_down(s2, off); }
    s = __shfl(s, 0); s2 = __shfl(s2, 0);
    float mu = s / 64.f, var = s2 / 64.f - mu * mu;
    float h = (v - mu) * rsqrtf(var + 1e-5f) * g1[tid] + bb1[tid];
    hb[tid] = fmaxf(h, 0.f);
  }
  __syncthreads();
  float outv[8];
  float s = 0.f, s2 = 0.f;
  int d0 = tid * 8;
#pragma unroll
  for (int o = 0; o < 8; ++o) {
    int d = d0 + o;
    float acc = b2[d];
    const float4* wr = (const float4*)(w2 + (size_t)d * 64);
#pragma unroll
    for (int k4 = 0; k4 < 16; ++k4) {
      float4 w = wr[k4];
      acc += w.x * hb[k4 * 4] + w.y * hb[k4 * 4 + 1] + w.z * hb[k4 * 4 + 2] + w.w * hb[k4 * 4 + 3];
    }
    outv[o] = acc; s += acc; s2 += acc * acc;
  }
  for (int off = 32; off; off >>= 1) { s += __shfl_down(s, off); s2 += __shfl_down(s2, off); }
  int wid = tid >> 6;
  if ((tid & 63) == 0) { rs[wid] = s; rs[2 + wid] = s2; }
  __syncthreads();
  s = rs[0] + rs[1]; s2 = rs[2] + rs[3];
  float mu = s / 1024.f, var = s2 / 1024.f - mu * mu;
  float rstd = rsqrtf(var + 1e-5f);
  float* op = emb + (size_t)combo * Dv + d0;
#pragma unroll
  for (int o = 0; o < 8; ++o) {
    int d = d0 + o;
    op[o] = (outv[o] - mu) * rstd * g2[d] + bb2[d];
  }
}

__global__ __launch_bounds__(256) void addemb_kernel(
    const float* __restrict__ x, const int* __restrict__ stage,
    const float* __restrict__ emb, bf16* __restrict__ xpe)
{
  int tok = blockIdx.x;
  int row = (tok & (Tv - 1)) * NS + stage[tok];
  const float4* xr = (const float4*)(x + (size_t)tok * Dv);
  const float4* er = (const float4*)(emb + (size_t)row * Dv);
  bf16* op = xpe + (size_t)tok * Dv + threadIdx.x * 4;
  float4 xv = xr[threadIdx.x], ev = er[threadIdx.x];
  op[0] = __float2bfloat16(xv.x + ev.x);
  op[1] = __float2bfloat16(xv.y + ev.y);
  op[2] = __float2bfloat16(xv.z + ev.z);
  op[3] = __float2bfloat16(xv.w + ev.w);
}

// ---------------- attention: per (b,h) flash-style, scalar fp32 ----------------
__global__ __launch_bounds__(256) void attn_kernel(const bf16* __restrict__ qkv,
                                                   bf16* __restrict__ o)
{
  __shared__ bf16 kl[128][128];
  __shared__ bf16 vl[128][128];
  int bh = blockIdx.x;
  int b = bh >> 3, h = bh & 7;
  int tid = threadIdx.x;
  int row = tid >> 1, hf = tid & 1;
  {
    const bf16* ks = qkv + (size_t)(b * Tv + row) * 3072 + Dv + h * HDv + hf * 64;
    const bf16* vs = ks + Dv;
    uint4* dk = (uint4*)&kl[row][hf * 64];
    uint4* dv = (uint4*)&vl[row][hf * 64];
    const uint4* sk = (const uint4*)ks;
    const uint4* sv = (const uint4*)vs;
#pragma unroll
    for (int i = 0; i < 8; ++i) { dk[i] = sk[i]; dv[i] = sv[i]; }
  }
  float qf[64];
  {
    const bf16* qs = qkv + (size_t)(b * Tv + row) * 3072 + h * HDv + hf * 64;
#pragma unroll
    for (int d2 = 0; d2 < 32; ++d2) {
      float2 f = __bfloat1622float2(*(const __hip_bfloat162*)(qs + 2 * d2));
      qf[2 * d2] = f.x; qf[2 * d2 + 1] = f.y;
    }
  }
  __syncthreads();
  float oacc[64];
#pragma unroll
  for (int d = 0; d < 64; ++d) oacc[d] = 0.f;
  float m = -1e30f, l = 0.f;
  const float scale = 0.088388347648318447f;  // 1/sqrt(128)
  for (int j = 0; j < 128; ++j) {
    float part = 0.f;
#pragma unroll
    for (int d2 = 0; d2 < 32; ++d2) {
      float2 kv2 = __bfloat1622float2(*(const __hip_bfloat162*)&kl[j][hf * 64 + 2 * d2]);
      part += qf[2 * d2] * kv2.x + qf[2 * d2 + 1] * kv2.y;
    }
    float sfull = (part + __shfl_xor(part, 1)) * scale;
    float mn = fmaxf(m, sfull);
    float al = __expf(m - mn);
    float p = __expf(sfull - mn);
    l = l * al + p;
#pragma unroll
    for (int d2 = 0; d2 < 32; ++d2) {
      float2 vv = __bfloat1622float2(*(const __hip_bfloat162*)&vl[j][hf * 64 + 2 * d2]);
      oacc[2 * d2]     = oacc[2 * d2] * al + p * vv.x;
      oacc[2 * d2 + 1] = oacc[2 * d2 + 1] * al + p * vv.y;
    }
    m = mn;
  }
  float rl = 1.f / l;
  bf16* od = o + (size_t)(b * Tv + row) * Dv + h * HDv + hf * 64;
#pragma unroll
  for (int d = 0; d < 64; ++d) od[d] = __float2bfloat16(oacc[d] * rl);
}

// ---------------- residual + LN -> raw (f32 to d_out) + raw16 -----------------
__global__ __launch_bounds__(256) void residual_ln_kernel(
    const bf16* __restrict__ xpe, const bf16* __restrict__ ao,
    const float* __restrict__ gam, const float* __restrict__ bet,
    float* __restrict__ rawf, bf16* __restrict__ raw16)
{
  int tok = blockIdx.x, tid = threadIdx.x;
  float v[4]; float s = 0.f, s2 = 0.f;
  __shared__ float rs[8];
#pragma unroll
  for (int q = 0; q < 4; ++q) {
    int d = tid + q * 256;
    size_t idx = (size_t)tok * Dv + d;
    float a = __bfloat162float(xpe[idx]) + __bfloat162float(ao[idx]);
    v[q] = a; s += a; s2 += a * a;
  }
  for (int off = 32; off; off >>= 1) { s += __shfl_down(s, off); s2 += __shfl_down(s2, off); }
  int wid = tid >> 6;
  if ((tid & 63) == 0) { rs[wid] = s; rs[4 + wid] = s2; }
  __syncthreads();
  s = rs[0] + rs[1] + rs[2] + rs[3];
  s2 = rs[4] + rs[5] + rs[6] + rs[7];
  float mu = s / 1024.f, var = s2 / 1024.f - mu * mu;
  float rstd = rsqrtf(var + 1e-5f);
#pragma unroll
  for (int q = 0; q < 4; ++q) {
    int d = tid + q * 256;
    size_t idx = (size_t)tok * Dv + d;
    float rv = (v[q] - mu) * rstd * gam[d] + bet[d];
    rawf[idx] = rv;
    raw16[idx] = __float2bfloat16(rv);
  }
}

// ---------------- fused 2-layer pipelined persistent LSTM (r9 verbatim) -------
__global__ __launch_bounds__(512, 1) void lstm_fused(
    const bf16* __restrict__ Whh0, const bf16* __restrict__ Wih1,
    const bf16* __restrict__ Whh1, const bf16* __restrict__ xgT,
    const float* __restrict__ bsum1,
    bf16* h0buf, bf16* h1buf,
    float* __restrict__ pooled, int* flags)
{
  const int bid = blockIdx.x;
  const int xcd = bid & 7, idx = bid >> 3;
  const int j   = xcd * 8 + (idx & 7);   // unit block 0..63
  const int gid = idx >> 3;              // batch group 0..3
  const int u0  = j * 16;
  const int tid = threadIdx.x;
  const int wave = tid >> 6, lane = tid & 63;
  const int g = wave & 3, kh = wave >> 2;
  const int l15 = lane & 15, lhi = lane >> 4;
  const int koff = lhi * 8;

  bf16x8 w0h[16], w1h[16], wh1h[16];
  {
    const size_t rowoff = (size_t)(g * Dv + u0 + l15) * Dv + kh * 512 + koff;
    const bf16* r0 = Whh0 + rowoff;
    const bf16* r1 = Wih1 + rowoff;
    const bf16* r2 = Whh1 + rowoff;
#pragma unroll
    for (int i = 0; i < 16; ++i) {
      w0h[i]  = *reinterpret_cast<const bf16x8*>(r0 + i * 32);
      w1h[i]  = *reinterpret_cast<const bf16x8*>(r1 + i * 32);
      wh1h[i] = *reinterpret_cast<const bf16x8*>(r2 + i * 32);
    }
#pragma unroll
    for (int i = 0; i < 16; ++i) {
      asm volatile("" : "+v"(w0h[i]));
      asm volatile("" : "+v"(w1h[i]));
      asm volatile("" : "+v"(wh1h[i]));
    }
  }
  const float bs1 = bsum1[g * Dv + u0 + l15];

  __shared__ bf16 hA[16 * 2056];
  __shared__ float gl0[2][4][16][16];
  __shared__ float gl1[2][4][16][16];
  __shared__ bf16 hst0[256];
  __shared__ bf16 hst1[256];

  const int bb_t = (tid & 255) >> 4, uu_t = tid & 15;
  float c0 = 0.f, c1 = 0.f;
  int* gflags = flags + gid * 64;

  for (int s = 0; s <= Tv; ++s) {
    float xv[4] = {0.f, 0.f, 0.f, 0.f};
    if (s < Tv && kh == 0) {
      const bf16* xg_t = xgT + (size_t)s * (Bv * 4 * Dv)
                         + (size_t)(gid * 16) * (4 * Dv) + g * Dv + u0 + l15;
#pragma unroll
      for (int r = 0; r < 4; ++r)
        xv[r] = __bfloat162float(xg_t[(size_t)(lhi * 4 + r) * (4 * Dv)]);
    }
    if (s > 0) {
      if (tid < 64) {
        while (true) {
          int v = __hip_atomic_load(gflags + tid, __ATOMIC_RELAXED, __HIP_MEMORY_SCOPE_AGENT);
          if (__all(v >= s)) break;
          __builtin_amdgcn_s_sleep(1);
        }
      }
      __syncthreads();                                   // S1
      {
        const u64* s0 = (const u64*)h0buf + (size_t)(((s - 1) & 1) * 4 + gid) * 4096;
        u64* dA = (u64*)hA;
#pragma unroll
        for (int it = 0; it < 8; ++it) {
          int id = it * 512 + tid;
          int jc = id >> 6, r = id & 63, bb = r >> 2, uq = r & 3;
          u64 v = __hip_atomic_load(s0 + id, __ATOMIC_RELAXED, __HIP_MEMORY_SCOPE_AGENT);
          dA[bb * 514 + jc * 4 + uq] = v;
        }
        if (s >= 2) {
          const u64* s1 = (const u64*)h1buf + (size_t)(((s - 2) & 1) * 4 + gid) * 4096;
#pragma unroll
          for (int it = 0; it < 8; ++it) {
            int id = it * 512 + tid;
            int jc = id >> 6, r = id & 63, bb = r >> 2, uq = r & 3;
            u64 v = __hip_atomic_load(s1 + id, __ATOMIC_RELAXED, __HIP_MEMORY_SCOPE_AGENT);
            dA[bb * 514 + 256 + jc * 4 + uq] = v;
          }
        }
      }
      __syncthreads();                                   // S2
    }

    if (s < Tv) {
      f32x4 acc = f32x4{0.f, 0.f, 0.f, 0.f};
      if (s > 0) {
#pragma unroll
        for (int i = 0; i < 16; ++i) {
          bf16x8 a = *reinterpret_cast<const bf16x8*>(&hA[l15 * 2056 + kh * 512 + i * 32 + koff]);
          acc = __builtin_amdgcn_mfma_f32_16x16x32_bf16(a, w0h[i], acc, 0, 0, 0);
        }
      }
#pragma unroll
      for (int r = 0; r < 4; ++r)
        gl0[kh][g][lhi * 4 + r][l15] = acc[r] + xv[r];
    }
    if (s > 0) {
      f32x4 acc = f32x4{0.f, 0.f, 0.f, 0.f};
#pragma unroll
      for (int i = 0; i < 16; ++i) {
        bf16x8 a = *reinterpret_cast<const bf16x8*>(&hA[l15 * 2056 + kh * 512 + i * 32 + koff]);
        acc = __builtin_amdgcn_mfma_f32_16x16x32_bf16(a, w1h[i], acc, 0, 0, 0);
      }
      if (s >= 2) {
#pragma unroll
        for (int i = 0; i < 16; ++i) {
          bf16x8 a = *reinterpret_cast<const bf16x8*>(&hA[l15 * 2056 + 1024 + kh * 512 + i * 32 + koff]);
          acc = __builtin_amdgcn_mfma_f32_16x16x32_bf16(a, wh1h[i], acc, 0, 0, 0);
        }
      }
#pragma unroll
      for (int r = 0; r < 4; ++r)
        gl1[kh][g][lhi * 4 + r][l15] = acc[r] + (kh == 0 ? bs1 : 0.f);
    }
    __syncthreads();                                     // S3
    if (tid < 256) {
      if (s < Tv) {
        float gi = gl0[0][0][bb_t][uu_t] + gl0[1][0][bb_t][uu_t];
        float gf = gl0[0][1][bb_t][uu_t] + gl0[1][1][bb_t][uu_t];
        float gc = gl0[0][2][bb_t][uu_t] + gl0[1][2][bb_t][uu_t];
        float go = gl0[0][3][bb_t][uu_t] + gl0[1][3][bb_t][uu_t];
        float cn = sigmoidf_(gf) * c0 + sigmoidf_(gi) * tanhf(gc);
        float hn = sigmoidf_(go) * tanhf(cn);
        c0 = cn;
        hst0[bb_t * 16 + uu_t] = __float2bfloat16(hn);
      }
      if (s > 0) {
        float gi = gl1[0][0][bb_t][uu_t] + gl1[1][0][bb_t][uu_t];
        float gf = gl1[0][1][bb_t][uu_t] + gl1[1][1][bb_t][uu_t];
        float gc = gl1[0][2][bb_t][uu_t] + gl1[1][2][bb_t][uu_t];
        float go = gl1[0][3][bb_t][uu_t] + gl1[1][3][bb_t][uu_t];
        float cn = sigmoidf_(gf) * c1 + sigmoidf_(gi) * tanhf(gc);
        float hn = sigmoidf_(go) * tanhf(cn);
        c1 = cn;
        hst1[bb_t * 16 + uu_t] = __float2bfloat16(hn);
        if (s == Tv) pooled[(gid * 16 + bb_t) * Dv + u0 + uu_t] = hn;
      }
    }
    __syncthreads();                                     // S4
    if (s < Tv && tid < 64) {
      u64* dst = (u64*)h0buf + (size_t)((s & 1) * 4 + gid) * 4096 + j * 64 + tid;
      __hip_atomic_store(dst, ((u64*)hst0)[tid], __ATOMIC_RELAXED, __HIP_MEMORY_SCOPE_AGENT);
    }
    if (s > 0 && tid >= 64 && tid < 128) {
      int q = tid - 64;
      u64* dst = (u64*)h1buf + (size_t)(((s - 1) & 1) * 4 + gid) * 4096 + j * 64 + q;
      __hip_atomic_store(dst, ((u64*)hst1)[q], __ATOMIC_RELAXED, __HIP_MEMORY_SCOPE_AGENT);
    }
    if (s < Tv) {
      asm volatile("s_waitcnt vmcnt(0)" ::: "memory");
      __syncthreads();                                   // S5
      if (tid == 0)
        __hip_atomic_store(gflags + j, s + 1, __ATOMIC_RELAXED, __HIP_MEMORY_SCOPE_AGENT);
    }
  }
}

// ---------------- raw_mean over T ----------------
__global__ void rawmean_kernel(const float* __restrict__ raw, float* __restrict__ out)
{
  int i = blockIdx.x * 256 + threadIdx.x;   // 65536
  int b = i >> 10, d = i & 1023;
  const float* r = raw + (size_t)b * Tv * Dv + d;
  float s = 0.f;
  for (int t = 0; t < Tv; ++t) s += r[(size_t)t * Dv];
  out[i] = s * (1.f / Tv);
}

// ---------------- fused gated-fusion + stage head (bf16 weights) --------------
__global__ __launch_bounds__(256) void gatehead_kernel(
    const float* __restrict__ pooled, const float* __restrict__ rawmean,
    const bf16* __restrict__ gw1b, const float* __restrict__ gb1,
    const bf16* __restrict__ gw2b, const float* __restrict__ gb2,
    const bf16* __restrict__ hw1b, const float* __restrict__ hb1,
    const float* __restrict__ hg, const float* __restrict__ hbb,
    const float* __restrict__ hw2, const float* __restrict__ hb2,
    float* __restrict__ fused_out, float* __restrict__ logits)
{
  int b = blockIdx.x, tid = threadIdx.x;
  __shared__ float cat[2048];
  __shared__ float g1v[1024];
  __shared__ float fl[1024];
  __shared__ float h1[512];
  __shared__ float rs[8];
  for (int k = tid; k < 1024; k += 256) {
    cat[k] = pooled[b * 1024 + k];
    cat[1024 + k] = rawmean[b * 1024 + k];
  }
  __syncthreads();
  // gate1 (relu), K=2048, bf16 weights
  for (int jj = 0; jj < 4; ++jj) {
    int j = tid + jj * 256;
    float acc = gb1[j];
    const uint4* wr = (const uint4*)(gw1b + (size_t)j * 2048);
    for (int ku = 0; ku < 256; ++ku) acc += dot8(wr[ku], &cat[ku * 8]);
    g1v[j] = fmaxf(acc, 0.f);
  }
  __syncthreads();
  // gate2 (sigmoid) + fused mix, K=1024
  for (int jj = 0; jj < 4; ++jj) {
    int j = tid + jj * 256;
    float acc = gb2[j];
    const uint4* wr = (const uint4*)(gw2b + (size_t)j * 1024);
    for (int ku = 0; ku < 128; ++ku) acc += dot8(wr[ku], &g1v[ku * 8]);
    float gv = sigmoidf_(acc);
    float f = gv * cat[j] + (1.f - gv) * cat[1024 + j];
    fused_out[b * 1024 + j] = f;
    fl[j] = f;
  }
  __syncthreads();
  // head: 512 hidden (2 per thread), LN, relu, logits
  float v0, v1;
  {
    float acc = hb1[tid];
    const uint4* wr = (const uint4*)(hw1b + (size_t)tid * 1024);
    for (int ku = 0; ku < 128; ++ku) acc += dot8(wr[ku], &fl[ku * 8]);
    v0 = acc;
    acc = hb1[tid + 256];
    wr = (const uint4*)(hw1b + (size_t)(tid + 256) * 1024);
    for (int ku = 0; ku < 128; ++ku) acc += dot8(wr[ku], &fl[ku * 8]);
    v1 = acc;
  }
  float s = v0 + v1, s2 = v0 * v0 + v1 * v1;
  for (int off = 32; off; off >>= 1) { s += __shfl_down(s, off); s2 += __shfl_down(s2, off); }
  int wid = tid >> 6;
  if ((tid & 63) == 0) { rs[wid] = s; rs[4 + wid] = s2; }
  __syncthreads();
  s = rs[0] + rs[1] + rs[2] + rs[3];
  s2 = rs[4] + rs[5] + rs[6] + rs[7];
  float mu = s / 512.f, var = s2 / 512.f - mu * mu;
  float rstd = rsqrtf(var + 1e-5f);
  h1[tid]       = fmaxf((v0 - mu) * rstd * hg[tid] + hbb[tid], 0.f);
  h1[tid + 256] = fmaxf((v1 - mu) * rstd * hg[tid + 256] + hbb[tid + 256], 0.f);
  __syncthreads();
  if (tid < 5) {
    float acc = hb2[tid];
    for (int k = 0; k < 512; ++k) acc += h1[k] * hw2[tid * 512 + k];
    logits[b * 5 + tid] = acc;
  }
}

// ---------------- memory bank update ----------------
__global__ void scatter_last_kernel(const int* __restrict__ cls,
                                    const int* __restrict__ stage, int* __restrict__ last)
{
  int i = blockIdx.x * 256 + threadIdx.x;
  if (i < NT) {
    int b = i >> 7;
    int p = cls[b] * NS + stage[i];
    atomicMax(&last[p], i);
  }
}

__global__ __launch_bounds__(256) void mem_update_kernel(
    const float* __restrict__ mem_in, const float* __restrict__ raw,
    const int* __restrict__ cnt_in, const int* __restrict__ last,
    float* __restrict__ mem_out, float* __restrict__ cnt_out)
{
  int p = blockIdx.x;
  int cnt = cnt_in[p];
  int li = last[p];
  bool present = li >= 0;
  bool full = cnt >= NM;
  int wp = full ? NM - 1 : cnt;
  const float* newf = raw + (size_t)(li < 0 ? 0 : li) * Dv;
  const float* src = mem_in + (size_t)p * NM * Dv;
  float* dst = mem_out + (size_t)p * NM * Dv;
  for (int idx = threadIdx.x; idx < NM * Dv / 4; idx += 256) {
    int m = idx >> 8;          // 256 float4 per row
    int dq = idx & 255;
    float4 v;
    if (present && full) {
      v = (m < NM - 1) ? *(const float4*)(src + (size_t)(m + 1) * Dv + dq * 4)
                       : *(const float4*)(newf + dq * 4);
    } else if (present) {
      v = (m == wp) ? *(const float4*)(newf + dq * 4)
                    : *(const float4*)(src + (size_t)m * Dv + dq * 4);
    } else {
      v = *(const float4*)(src + (size_t)m * Dv + dq * 4);
    }
    *(float4*)(dst + (size_t)m * Dv + dq * 4) = v;
  }
  if (threadIdx.x == 0)
    cnt_out[p] = (float)(cnt + ((present && !full) ? 1 : 0));
}

// =======================================================================
extern "C" void kernel_launch(void* const* d_in, const int* in_sizes, int n_in,
                              void* d_out, int out_size, void* d_ws, size_t ws_size,
                              hipStream_t stream)
{
  (void)in_sizes; (void)n_in; (void)out_size; (void)ws_size;
  const float* x       = (const float*)d_in[0];
  const int* stage     = (const int*)d_in[1];
  const int* cls       = (const int*)d_in[2];
  const float* enc_w1  = (const float*)d_in[3];
  const float* enc_b1  = (const float*)d_in[4];
  const float* enc_g1  = (const float*)d_in[5];
  const float* enc_bb1 = (const float*)d_in[6];
  const float* enc_w2  = (const float*)d_in[7];
  const float* enc_b2  = (const float*)d_in[8];
  const float* enc_g2  = (const float*)d_in[9];
  const float* enc_bb2 = (const float*)d_in[10];
  const float* qkv_w   = (const float*)d_in[11];
  const float* qkv_b   = (const float*)d_in[12];
  const float* out_w   = (const float*)d_in[13];
  const float* out_b   = (const float*)d_in[14];
  const float* norm_g  = (const float*)d_in[15];
  const float* norm_b  = (const float*)d_in[16];
  const float* Wih0    = (const float*)d_in[17];
  const float* Whh0    = (const float*)d_in[18];
  const float* bih0    = (const float*)d_in[19];
  const float* bhh0    = (const float*)d_in[20];
  const float* Wih1    = (const float*)d_in[21];
  const float* Whh1    = (const float*)d_in[22];
  const float* bih1    = (const float*)d_in[23];
  const float* bhh1    = (const float*)d_in[24];
  const float* head_w1 = (const float*)d_in[25];
  const float* head_b1 = (const float*)d_in[26];
  const float* head_g  = (const float*)d_in[27];
  const float* head_bb = (const float*)d_in[28];
  const float* head_w2 = (const float*)d_in[29];
  const float* head_b2 = (const float*)d_in[30];
  const float* gate_w1 = (const float*)d_in[31];
  const float* gate_b1 = (const float*)d_in[32];
  const float* gate_w2 = (const float*)d_in[33];
  const float* gate_b2 = (const float*)d_in[34];
  const float* mem_in  = (const float*)d_in[35];
  const int* cnt_in    = (const int*)d_in[36];

  float* out = (float*)d_out;
  float* out_fused  = out;                      // 65536
  float* out_raw    = out + 65536;              // 8388608
  float* out_logits = out + 8454144;            // 320
  float* out_mem    = out + 8454464;            // 51200000
  float* out_cnt    = out + 59654464;           // 5000

  // ---- workspace layout (bf16 weights + small state), ~49 MB ----
  char* wsb = (char*)d_ws;
  auto alloc = [&](size_t bytes) { char* p = wsb; wsb += (bytes + 255) & ~(size_t)255; return p; };
  bf16* wq16   = (bf16*)alloc((size_t)3072 * 1024 * 2);
  bf16* wo16   = (bf16*)alloc((size_t)1024 * 1024 * 2);
  bf16* wih0b  = (bf16*)alloc((size_t)4096 * 1024 * 2);
  bf16* whh0b  = (bf16*)alloc((size_t)4096 * 1024 * 2);
  bf16* wih1b  = (bf16*)alloc((size_t)4096 * 1024 * 2);
  bf16* whh1b  = (bf16*)alloc((size_t)4096 * 1024 * 2);
  bf16* gw1b   = (bf16*)alloc((size_t)1024 * 2048 * 2);
  bf16* gw2b   = (bf16*)alloc((size_t)1024 * 1024 * 2);
  bf16* hw1b   = (bf16*)alloc((size_t)512 * 1024 * 2);
  float* bsum0 = (float*)alloc(4096 * 4);
  float* bsum1 = (float*)alloc(4096 * 4);
  bf16* h0buf  = (bf16*)alloc((size_t)2 * 4 * 16384 * 2);  // [parity][gid]: 4096 u64 each
  bf16* h1buf  = (bf16*)alloc((size_t)2 * 4 * 16384 * 2);
  float* pooled  = (float*)alloc(65536 * 4);
  float* rawmean = (float*)alloc(65536 * 4);
  int* last      = (int*)alloc(5000 * 4);
  int* flags     = (int*)alloc(1024);            // 4 groups x 64 ints

  // ---- large activation scratch inside the new_mem output slot (204.8 MB) ----
  char* orb = (char*)out_mem;
  bf16* qkv16 = (bf16*)(orb + 0);            // 50,331,648 B
  bf16* xgT   = (bf16*)(orb + 67108864);     // 67,108,864 B  [t][b][4096]
  bf16* xpe16 = (bf16*)(orb + 134217728);    // 16,777,216 B
  bf16* o16   = (bf16*)(orb + 150994944);    // 16,777,216 B
  bf16* ao16  = (bf16*)(orb + 167772160);    // 16,777,216 B
  bf16* raw16 = (bf16*)(orb + 184549376);    // 16,777,216 B (ends 201,326,592)
  float* embf = (float*)(orb + 201326592);   //  2,621,440 B (ends 203,948,032)

  // 1) fused weight conversions + bias sums (single launch)
  convert_all<<<24072, 256, 0, stream>>>(qkv_w, out_w, Wih0, Whh0, Wih1, Whh1,
                                         gate_w1, gate_w2, head_w1,
                                         bih0, bhh0, bih1, bhh1,
                                         wq16, wo16, wih0b, whh0b, wih1b, whh1b,
                                         gw1b, gw2b, hw1b, bsum0, bsum1);

  // 2) encoder: 640-row emb table, then fused add -> xpe16
  emb_kernel<<<Tv * NS, 128, 0, stream>>>(enc_w1, enc_b1, enc_g1, enc_bb1,
                                          enc_w2, enc_b2, enc_g2, enc_bb2, embf);
  addemb_kernel<<<NT, 256, 0, stream>>>(x, stage, embf, xpe16);

  // 3) qkv = xpe @ qkv_w^T + b
  gemm128<<<dim3(NT / 128, 3072 / 128), 256, 0, stream>>>(xpe16, wq16, qkv_b, qkv16,
                                                          NT, 3072, Dv, 0);

  // 4) attention -> o16
  attn_kernel<<<Bv * Hv, 256, 0, stream>>>(qkv16, o16);

  // 5) out projection -> ao16
  gemm128<<<dim3(NT / 128, 1024 / 128), 256, 0, stream>>>(o16, wo16, out_b, ao16,
                                                          NT, Dv, Dv, 0);

  // 6) residual + LN -> raw (d_out) + raw16
  residual_ln_kernel<<<NT, 256, 0, stream>>>(xpe16, ao16, norm_g, norm_b, out_raw, raw16);

  // 7) layer-0 input gates (time-major), then fused 2-layer recurrence
  gemm128<<<dim3(NT / 128, 4096 / 128), 256, 0, stream>>>(raw16, wih0b, bsum0, xgT,
                                                          NT, 4096, Dv, 1);
  hipMemsetAsync(flags, 0, 1024, stream);
  lstm_fused<<<256, 512, 0, stream>>>(whh0b, wih1b, whh1b, xgT, bsum1,
                                      h0buf, h1buf, pooled, flags);

  // 8) raw_mean, fused gate+head (bf16 weights)
  rawmean_kernel<<<256, 256, 0, stream>>>(out_raw, rawmean);
  gatehead_kernel<<<Bv, 256, 0, stream>>>(pooled, rawmean,
                                          gw1b, gate_b1, gw2b, gate_b2,
                                          hw1b, head_b1, head_g, head_bb,
                                          head_w2, head_b2, out_fused, out_logits);

  // 9) memory bank update (overwrites the scratch region last)
  hipMemsetAsync(last, 0xFF, 5000 * 4, stream);
  scatter_last_kernel<<<32, 256, 0, stream>>>(cls, stage, last);
  mem_update_kernel<<<NC * NS, 256, 0, stream>>>(mem_in, out_raw, cnt_in, last, out_mem, out_cnt);
}